// Round 16
// baseline (695.810 us; speedup 1.0000x reference)
//
#include <hip/hip_runtime.h>
#include <math.h>

// ---------------- problem constants ----------------
#define NCAM 6
#define IH 256
#define IW 704
#define FH 32
#define FW 88
#define DD 59
#define CIMG 80
#define NXv 360
#define PIX (FH*FW)           // 2816
#define IMGPIX (IH*IW)        // 180224
#define NPTS (NCAM*DD*PIX)    // 996864
#define NCELLS (NXv*NXv)      // 129600
#define NB 127                // scan blocks
#define UNIT 32
#define MAXUNITS (NCELLS + NPTS/UNIT + 1)   // 160753
#define GATHER_BLOCKS ((MAXUNITS + 3) / 4)  // 40189

// padded GEMM pixel space (depthnet): rows [35] x pitch [96]
#define MPITCH 96
#define MROWS  35
#define MSLAB  (MROWS*MPITCH) // 3360

// dtransform NHWC padded buffers
#define DP_R 260
#define DP_C 708
#define H2_R 68
#define H2_C 180

// BEV ds GEMM
#define DSM   32400
#define DSP1  362
#define DSP2  182
#define DSC   96

typedef _Float16 f16;
typedef f16  f16x8 __attribute__((ext_vector_type(8)));
typedef float f32x4 __attribute__((ext_vector_type(4)));

// XOR-swizzled LDS staging (pitch 32 halves)
#define SWZ(r, g) (((r)<<5) + (((g) ^ ((r)&3))<<3))

// ---------------- ws arena offsets (in floats) ----------------
#define OFF_MATS 0                      // 144
#define OFF_WDS1 144                    // 34,560 (3x80x288 fp16)
#define OFF_WDT2 34704                  // 5,120 (5x32x64 fp16)
#define OFF_WDS2 57744                  // 34,560
// SEG_A: {dNH, h2NH} -> {Q3 + Q2 + Wt1 + Wt2 + Wt3h} -> pooled
#define OFF_A    115344
#define OFF_DNH  OFF_A
#define OFF_H2NH (OFF_A + 4416960)
#define OFF_Q3   OFF_A                  // 6x2816x256 fp16 [dn2..dn3]
#define OFF_Q2   (OFF_A + 4325376)
#define OFF_WT1  (OFF_A + 6905856)      // 9x256x320 fp16
#define OFF_WT2  (OFF_A + 7274496)      // 9x256x256 fp16
#define OFF_TD3  (OFF_A + 7569408)      // Wt3h: 144x256 fp16
// SEG_B
#define OFF_B    10483344
#define OFF_WDT3 OFF_B
#define OFF_CNT    (OFF_B)
#define OFF_INCL   (OFF_B + 131072)
#define OFF_OFFS   (OFF_B + 262144)
#define OFF_CURSOR (OFF_B + 393216)
#define OFF_BSUM   (OFF_B + 524288)
#define OFF_UCNT   (OFF_B + 524480)
#define OFF_BSX    (OFF_B + 524544)
#define OFF_UNITS  (OFF_B + 525312)
#define OFF_POOLH  (OFF_B)
#define OFF_BEV1H  (OFF_B + 6289632)
// SEG_C
#define OFF_C    12831888
// SEG_D
#define OFF_D      13913232
#define OFF_Q1     OFF_D
#define OFF_FEATT  OFF_D                // fp16 [16896][80]
#define OFF_FLAT   (OFF_D + 1351680)
#define OFF_ORDYX  (OFF_D + 2348544)
#define OFF_ORDD   (OFF_D + 3345408)
// total 18,853,776 floats ~75.4 MB

// ---------------- small helpers ----------------
__device__ __forceinline__ void inv3(const float* m, float* o) {
    float a=m[0],b=m[1],c=m[2],d=m[3],e=m[4],f=m[5],g=m[6],h=m[7],i=m[8];
    float A =  (e*i - f*h);
    float B = -(d*i - f*g);
    float C =  (d*h - e*g);
    float det = a*A + b*B + c*C;
    float r = 1.f/det;
    o[0]=A*r;            o[1]=-(b*i - c*h)*r; o[2]=(b*f - c*e)*r;
    o[3]=B*r;            o[4]=(a*i - c*g)*r;  o[5]=-(a*f - c*d)*r;
    o[6]=C*r;            o[7]=-(a*h - b*g)*r; o[8]=(a*e - b*d)*r;
}

__global__ void k_cam_mats(const float* __restrict__ prot, const float* __restrict__ ptran,
                           const float* __restrict__ intr, const float* __restrict__ Rcl,
                           const float* __restrict__ tcl, float* __restrict__ mats) {
    int n = threadIdx.x;
    if (n >= NCAM) return;
    float P[9], Km[9], R[9], A[9], Ki[9];
    for (int i=0;i<9;i++){ P[i]=prot[n*9+i]; Km[i]=intr[n*9+i]; R[i]=Rcl[n*9+i]; }
    inv3(P, A); inv3(Km, Ki);
    float* M = mats + n*24;
    for (int i=0;i<9;i++) M[i] = A[i];
    for (int r=0;r<3;r++)
        M[9+r] = -(A[r*3+0]*ptran[n*3+0] + A[r*3+1]*ptran[n*3+1] + A[r*3+2]*ptran[n*3+2]);
    for (int r=0;r<3;r++) for (int c=0;c<3;c++)
        M[12 + r*3+c] = R[r*3+0]*Ki[0*3+c] + R[r*3+1]*Ki[1*3+c] + R[r*3+2]*Ki[2*3+c];
    for (int r=0;r<3;r++) M[21+r] = tcl[n*3+r];
}

// ds weight prep: [80co][80ci][3][3] -> fp16 [kx][co][ky*96+ci]
__global__ void k_wtrans_ds(const float* __restrict__ w, f16* __restrict__ Wt) {
    int i = blockIdx.x*blockDim.x + threadIdx.x;
    if (i >= 3*80*288) return;
    int k  = i % 288;
    int co = (i / 288) % 80;
    int kx = i / (288*80);
    int ky = k / 96, ci = k % 96;
    Wt[i] = (ci < 80) ? (f16)w[((co*80 + ci)*3 + kx)*3 + ky] : (f16)0.f;
}

// dt2 weight prep
__global__ void k_wtrans_dt2(const float* __restrict__ w, f16* __restrict__ Wt) {
    int i = blockIdx.x*blockDim.x + threadIdx.x;
    if (i >= 5*32*64) return;
    int ky = i / (32*64);
    int r  = i % (32*64);
    int co = r / 64;
    int k  = r % 64;
    int kx = k / 8, ci = k % 8;
    Wt[i] = (kx < 5) ? (f16)w[co*200 + ci*25 + ky*5 + kx] : (f16)0.f;
}

// dt3 weight prep
__global__ void k_wtrans_dt3(const float* __restrict__ w, f16* __restrict__ Wt) {
    int i = blockIdx.x*blockDim.x + threadIdx.x;
    if (i >= 5*64*160) return;
    int ky = i / (64*160);
    int r  = i % (64*160);
    int co = r / 160;
    int k  = r % 160;
    int kx = k / 32, ci = k % 32;
    Wt[i] = (f16)w[co*800 + ci*25 + ky*5 + kx];
}

// dn3 weight prep: [139][256] fp32 -> [144][256] fp16
__global__ void k_prep_b3(const float* __restrict__ w, f16* __restrict__ Wt) {
    int i = blockIdx.x*blockDim.x + threadIdx.x;
    if (i >= 144*256) return;
    int co = i / 256;
    Wt[i] = (co < 139) ? (f16)w[i] : (f16)0.f;
}

// depthnet GEMM weight prep
template<int CIN>
__global__ void k_prep_b(const float* __restrict__ w, f16* __restrict__ Wt) {
    int co = blockIdx.x;
    int ci = threadIdx.x;
    const float* src = w + ((size_t)co*CIN + ci)*9;
    #pragma unroll
    for (int t=0;t<9;t++)
        Wt[((size_t)t*256 + co)*CIN + ci] = (f16)src[t];
}

// fused dt1 -> padded NHWC fp16 [6][260][708][8]
__global__ __launch_bounds__(256) void k_prep_d(const float* __restrict__ d,
                                                const float* __restrict__ w,
                                                const float* __restrict__ b,
                                                const float* __restrict__ s,
                                                const float* __restrict__ t,
                                                f16* __restrict__ dNH) {
    int i = blockIdx.x*256 + threadIdx.x;
    int cam = i / IMGPIX;
    int yx = i % IMGPIX;
    int y = yx / IW, x = yx % IW;
    float v = d[i];
    f16* dst = dNH + ((size_t)cam*DP_R + (y+2))*DP_C*8 + (size_t)(x+2)*8;
    #pragma unroll
    for (int c=0;c<8;c++)
        dst[c] = (f16)fmaxf(fmaf(fmaf(v, w[c], b[c]), s[c], t[c]), 0.f);
}

// dt2 as implicit GEMM (swizzled LDS)
__global__ __launch_bounds__(256) void k_gemm_dt2(const f16* __restrict__ dNH,
                                                  const f16* __restrict__ Wt,
                                                  const float* __restrict__ bias,
                                                  const float* __restrict__ bn_s,
                                                  const float* __restrict__ bn_t,
                                                  f16* __restrict__ h2NH) {
    __shared__ f16 lA[128*32];
    __shared__ f16 lB[32*32];
    int cam = blockIdx.x / 88, mt = blockIdx.x % 88;
    int m0 = mt*128;
    int tid = threadIdx.x;
    int wid = tid>>6, lane = tid&63;
    int wm = wid*32;
    int lr = lane&15, quad = lane>>4;
    int swr = ((quad ^ (lr&3))<<3);
    f32x4 acc[2][2] = {};

    int rr = tid >> 1;
    int g0 = tid & 1, g1 = g0 + 2;
    int am = m0 + rr;
    int ay = am / 176, ax = am % 176;
    const f16* abase = dNH + (size_t)cam*DP_R*DP_C*8 + (size_t)(ay*4)*DP_C*8 + (size_t)(ax*4)*8;

    for (int ky=0; ky<5; ky++) {
        const f16* arow = abase + (size_t)ky*DP_C*8;
        const f16* brow = Wt + ((size_t)ky*32 + rr)*64;
        #pragma unroll
        for (int k0=0; k0<64; k0+=32) {
            *(float4*)(&lA[SWZ(rr,g0)]) = *(const float4*)(arow + k0 + g0*8);
            *(float4*)(&lA[SWZ(rr,g1)]) = *(const float4*)(arow + k0 + g1*8);
            if (tid < 64) {
                *(float4*)(&lB[SWZ(rr,g0)]) = *(const float4*)(brow + k0 + g0*8);
                *(float4*)(&lB[SWZ(rr,g1)]) = *(const float4*)(brow + k0 + g1*8);
            }
            __syncthreads();
            f16x8 af[2], bf[2];
            #pragma unroll
            for (int i=0;i<2;i++) af[i] = *(f16x8*)(&lA[((wm+i*16+lr)<<5) + swr]);
            #pragma unroll
            for (int j=0;j<2;j++) bf[j] = *(f16x8*)(&lB[((j*16+lr)<<5) + swr]);
            #pragma unroll
            for (int i=0;i<2;i++)
                #pragma unroll
                for (int j=0;j<2;j++)
                    acc[i][j] = __builtin_amdgcn_mfma_f32_16x16x32_f16(af[i], bf[j], acc[i][j], 0,0,0);
            __syncthreads();
        }
    }
    #pragma unroll
    for (int j=0;j<2;j++) {
        int n = j*16 + lr;
        float bb = bias[n], ss = bn_s[n], tt = bn_t[n];
        #pragma unroll
        for (int i=0;i<2;i++) {
            #pragma unroll
            for (int r=0;r<4;r++) {
                int m = m0 + wm + i*16 + quad*4 + r;
                int y = m / 176, x = m % 176;
                float v = fmaxf(fmaf(acc[i][j][r] + bb, ss, tt), 0.f);
                h2NH[((size_t)cam*H2_R + (y+2))*H2_C*32 + (size_t)(x+2)*32 + n] = (f16)v;
            }
        }
    }
}

// dt3 as implicit GEMM -> Q1 ch 0..63 (swizzled LDS)
__global__ __launch_bounds__(256) void k_gemm_dt3(const f16* __restrict__ h2NH,
                                                  const f16* __restrict__ Wt,
                                                  const float* __restrict__ bias,
                                                  const float* __restrict__ bn_s,
                                                  const float* __restrict__ bn_t,
                                                  f16* __restrict__ Q1) {
    __shared__ f16 lA[128*32];
    __shared__ f16 lB[64*32];
    int cam = blockIdx.x / 22, mt = blockIdx.x % 22;
    int m0 = mt*128;
    int tid = threadIdx.x;
    int wid = tid>>6, lane = tid&63;
    int wm = wid*32;
    int lr = lane&15, quad = lane>>4;
    int swr = ((quad ^ (lr&3))<<3);
    f32x4 acc[2][4] = {};

    int rr = tid >> 1;
    int g0 = tid & 1, g1 = g0 + 2;
    int am = m0 + rr;
    int ay = am / FW, ax = am % FW;
    const f16* abase = h2NH + (size_t)cam*H2_R*H2_C*32 + (size_t)(ay*2)*H2_C*32 + (size_t)(ax*2)*32;

    for (int ky=0; ky<5; ky++) {
        const f16* arow = abase + (size_t)ky*H2_C*32;
        const f16* brow = Wt + ((size_t)ky*64 + rr)*160;
        #pragma unroll
        for (int k0=0; k0<160; k0+=32) {
            *(float4*)(&lA[SWZ(rr,g0)]) = *(const float4*)(arow + k0 + g0*8);
            *(float4*)(&lA[SWZ(rr,g1)]) = *(const float4*)(arow + k0 + g1*8);
            if (tid < 128) {
                *(float4*)(&lB[SWZ(rr,g0)]) = *(const float4*)(brow + k0 + g0*8);
                *(float4*)(&lB[SWZ(rr,g1)]) = *(const float4*)(brow + k0 + g1*8);
            }
            __syncthreads();
            f16x8 af[2], bf[4];
            #pragma unroll
            for (int i=0;i<2;i++) af[i] = *(f16x8*)(&lA[((wm+i*16+lr)<<5) + swr]);
            #pragma unroll
            for (int j=0;j<4;j++) bf[j] = *(f16x8*)(&lB[((j*16+lr)<<5) + swr]);
            #pragma unroll
            for (int i=0;i<2;i++)
                #pragma unroll
                for (int j=0;j<4;j++)
                    acc[i][j] = __builtin_amdgcn_mfma_f32_16x16x32_f16(af[i], bf[j], acc[i][j], 0,0,0);
            __syncthreads();
        }
    }
    #pragma unroll
    for (int j=0;j<4;j++) {
        int n = j*16 + lr;
        float bb = bias[n], ss = bn_s[n], tt = bn_t[n];
        #pragma unroll
        for (int i=0;i<2;i++) {
            #pragma unroll
            for (int r=0;r<4;r++) {
                int m = m0 + wm + i*16 + quad*4 + r;
                int y = m / FW, x = m % FW;
                float v = fmaxf(fmaf(acc[i][j][r] + bb, ss, tt), 0.f);
                Q1[((size_t)cam*MSLAB + (size_t)(y+1)*MPITCH + (x+1))*320 + n] = (f16)v;
            }
        }
    }
}

// copy x_img -> Q1 channels 64..319
__global__ __launch_bounds__(256) void k_prep_a1x(const float* __restrict__ x_img,
                                                  f16* __restrict__ Q1) {
    __shared__ f16 tile[88*260];
    int y = blockIdx.x, cam = blockIdx.y;
    for (int e = threadIdx.x; e < 88*256; e += 256) {
        int c = e / 88, p = e % 88;
        tile[p*260 + c] = (f16)x_img[((size_t)cam*256 + c)*PIX + y*FW + p];
    }
    __syncthreads();
    f16* dst = Q1 + (size_t)cam*(MSLAB*320) + ((size_t)(y+1)*MPITCH + 1)*320 + 64;
    for (int e = threadIdx.x; e < 88*256; e += 256) {
        int p = e / 256, c = e % 256;
        dst[(size_t)p*320 + c] = tile[p*260 + c];
    }
}

// fp16 implicit-GEMM 3x3 conv (depthnet, swizzled LDS, 128x128)
template<int KCI, int EPI>
__global__ __launch_bounds__(256) void k_gemm_conv(const f16* __restrict__ Aq,
                                                   const f16* __restrict__ Wt,
                                                   const float* __restrict__ bias,
                                                   const float* __restrict__ bn_s,
                                                   const float* __restrict__ bn_t,
                                                   f16* __restrict__ outh) {
    __shared__ f16 lA[128*32];
    __shared__ f16 lB[128*32];
    int cam = blockIdx.x / 24, mt = blockIdx.x % 24;
    int m0 = mt*128;
    int co0 = blockIdx.y * 128;
    int tid = threadIdx.x;
    f32x4 acc[4][4] = {};
    const f16* Abase = Aq + (size_t)cam*MSLAB*KCI;
    int rr = tid >> 1;
    int g0 = tid & 1, g1 = g0 + 2;
    int wid = tid>>6, lane = tid&63;
    int wm = (wid&1)*64, wn = (wid>>1)*64;
    int lr = lane&15, quad = lane>>4;
    int swr = ((quad ^ (lr&3))<<3);

    for (int t=0; t<9; t++) {
        int moff = (t/3)*MPITCH + (t%3);
        const f16* At = Abase + (size_t)(m0 + moff + rr)*KCI;
        const f16* Bt = Wt + ((size_t)t*256 + co0 + rr)*KCI;
        for (int k0=0; k0<KCI; k0+=32) {
            *(float4*)(&lA[SWZ(rr,g0)]) = *(const float4*)(At + k0 + g0*8);
            *(float4*)(&lA[SWZ(rr,g1)]) = *(const float4*)(At + k0 + g1*8);
            *(float4*)(&lB[SWZ(rr,g0)]) = *(const float4*)(Bt + k0 + g0*8);
            *(float4*)(&lB[SWZ(rr,g1)]) = *(const float4*)(Bt + k0 + g1*8);
            __syncthreads();
            f16x8 af[4], bf[4];
            #pragma unroll
            for (int i=0;i<4;i++) af[i] = *(f16x8*)(&lA[((wm+i*16+lr)<<5) + swr]);
            #pragma unroll
            for (int j=0;j<4;j++) bf[j] = *(f16x8*)(&lB[((wn+j*16+lr)<<5) + swr]);
            #pragma unroll
            for (int i=0;i<4;i++)
                #pragma unroll
                for (int j=0;j<4;j++)
                    acc[i][j] = __builtin_amdgcn_mfma_f32_16x16x32_f16(af[i], bf[j], acc[i][j], 0,0,0);
            __syncthreads();
        }
    }
    #pragma unroll
    for (int j=0;j<4;j++) {
        int n = co0 + wn + j*16 + lr;
        float bb = bias[n], ss = bn_s[n], tt = bn_t[n];
        #pragma unroll
        for (int i=0;i<4;i++) {
            #pragma unroll
            for (int r=0;r<4;r++) {
                int m = m0 + wm + i*16 + quad*4 + r;
                int y = m / MPITCH, x = m % MPITCH;
                if (x >= FW || y >= FH) continue;
                float v = fmaxf(fmaf(acc[i][j][r] + bb, ss, tt), 0.f);
                if (EPI == 0)
                    outh[((size_t)cam*MSLAB + (size_t)(y+1)*MPITCH + (x+1))*256 + n] = (f16)v;
                else
                    outh[((size_t)cam*PIX + (size_t)(y*FW + x))*256 + n] = (f16)v;
            }
        }
    }
}

// dn3 as MFMA GEMM (M=2816/cam, N=144, K=256) -> f3 fp32 NCHW
__global__ __launch_bounds__(256) void k_gemm_dn3(const f16* __restrict__ Q3,
                                                  const f16* __restrict__ Wt,
                                                  const float* __restrict__ bias,
                                                  float* __restrict__ f3) {
    __shared__ f16 lA[128*32];
    __shared__ f16 lB[144*32];
    int cam = blockIdx.x / 22, mt = blockIdx.x % 22;
    int m0 = mt*128;
    int tid = threadIdx.x;
    int wid = tid>>6, lane = tid&63;
    int wm = wid*32;
    int lr = lane&15, quad = lane>>4;
    int swr = ((quad ^ (lr&3))<<3);
    f32x4 acc[2][9] = {};

    int rr = tid >> 1;
    int g0 = tid & 1, g1 = g0 + 2;
    const f16* abase = Q3 + ((size_t)cam*PIX + m0 + rr)*256;
    const f16* bbase = Wt + (size_t)tid*256;

    for (int k0=0; k0<256; k0+=32) {
        *(float4*)(&lA[SWZ(rr,g0)]) = *(const float4*)(abase + k0 + g0*8);
        *(float4*)(&lA[SWZ(rr,g1)]) = *(const float4*)(abase + k0 + g1*8);
        if (tid < 144) {
            #pragma unroll
            for (int g=0; g<4; g++)
                *(float4*)(&lB[SWZ(tid,g)]) = *(const float4*)(bbase + k0 + g*8);
        }
        __syncthreads();
        f16x8 af[2], bf[9];
        #pragma unroll
        for (int i=0;i<2;i++) af[i] = *(f16x8*)(&lA[((wm+i*16+lr)<<5) + swr]);
        #pragma unroll
        for (int j=0;j<9;j++) bf[j] = *(f16x8*)(&lB[((j*16+lr)<<5) + swr]);
        #pragma unroll
        for (int i=0;i<2;i++)
            #pragma unroll
            for (int j=0;j<9;j++)
                acc[i][j] = __builtin_amdgcn_mfma_f32_16x16x32_f16(af[i], bf[j], acc[i][j], 0,0,0);
        __syncthreads();
    }
    #pragma unroll
    for (int j=0;j<9;j++) {
        int n = j*16 + lr;
        if (n >= 139) continue;
        float bb = bias[n];
        #pragma unroll
        for (int i=0;i<2;i++) {
            #pragma unroll
            for (int r=0;r<4;r++) {
                int m = m0 + wm + i*16 + quad*4 + r;
                f3[((size_t)cam*139 + n)*PIX + m] = acc[i][j][r] + bb;
            }
        }
    }
}

// softmax v2: register-cached single pass over the 59 depth logits
__global__ __launch_bounds__(256) void k_softmax2(const float* __restrict__ f3,
                                                  float* __restrict__ depth) {
    int o = blockIdx.x*256 + threadIdx.x;       // 16896
    int n = o / PIX, yx = o % PIX;
    const float* fp = f3 + (size_t)n*139*PIX + yx;
    float r[DD];
    #pragma unroll
    for (int d=0; d<DD; d++) r[d] = fp[(size_t)d*PIX];
    float m = -1e30f;
    #pragma unroll
    for (int d=0; d<DD; d++) m = fmaxf(m, r[d]);
    float sum = 0.f;
    #pragma unroll
    for (int d=0; d<DD; d++) { r[d] = expf(r[d]-m); sum += r[d]; }
    float inv = 1.f/sum;
    #pragma unroll
    for (int d=0; d<DD; d++)
        depth[((size_t)n*DD+d)*PIX + yx] = r[d]*inv;
}

// featT transpose: f3 ch 59..138 -> fp16 [n*PIX+yx][80], LDS-tiled
__global__ __launch_bounds__(256) void k_featT(const float* __restrict__ f3,
                                               f16* __restrict__ featTh) {
    __shared__ float tile[88*81];
    int y = blockIdx.x, cam = blockIdx.y;
    const float* src = f3 + (size_t)cam*139*PIX + (size_t)DD*PIX + y*FW;
    for (int e = threadIdx.x; e < 88*80; e += 256) {
        int c = e / 88, p = e % 88;
        tile[p*81 + c] = src[(size_t)c*PIX + p];
    }
    __syncthreads();
    f16* dst = featTh + ((size_t)cam*PIX + y*FW)*CIMG;
    for (int e = threadIdx.x; e < 88*80; e += 256) {
        int p = e / 80, c = e % 80;
        dst[(size_t)p*CIMG + c] = (f16)tile[p*81 + c];
    }
}

// frustum -> voxel index + histogram
__global__ __launch_bounds__(256) void k_voxel(const float* __restrict__ mats, int* __restrict__ flat,
                                               int* __restrict__ cnt) {
    int p = blockIdx.x*256 + threadIdx.x;
    if (p >= NPTS) return;
    int x = p % FW; int t1 = p / FW;
    int y = t1 % FH; int t2 = t1 / FH;
    int dd = t2 % DD; int n = t2 / DD;
    float xf = x * (703.f/87.f);
    float yf = y * (255.f/31.f);
    float df = 1.f + (float)dd;
    const float* M = mats + n*24;
    float qx = M[0]*xf + M[1]*yf + M[2]*df + M[9];
    float qy = M[3]*xf + M[4]*yf + M[5]*df + M[10];
    float qz = M[6]*xf + M[7]*yf + M[8]*df + M[11];
    float rx = qx*qz, ry = qy*qz, rz = qz;
    float wx = M[12]*rx + M[13]*ry + M[14]*rz + M[21];
    float wy = M[15]*rx + M[16]*ry + M[17]*rz + M[22];
    float wz = M[18]*rx + M[19]*ry + M[20]*rz + M[23];
    int gx = (int)((wx + 54.f) / 0.3f);
    int gy = (int)((wy + 54.f) / 0.3f);
    int gz = (int)((wz + 10.f) / 20.f);
    bool kept = ((unsigned)gx < NXv) && ((unsigned)gy < NXv) && (gz == 0);
    int cell = kept ? (gx*NXv + gy) : -1;
    flat[p] = cell;
    if (kept) atomicAdd(&cnt[cell], 1);
}

// scan step 1
__global__ __launch_bounds__(256) void k_scan1(const int* __restrict__ cnt, int* __restrict__ incl,
                                               int* __restrict__ bsum) {
    int tid = threadIdx.x;
    int idx = blockIdx.x*1024 + tid*4;
    int c0 = (idx+0 < NCELLS) ? cnt[idx+0] : 0;
    int c1 = (idx+1 < NCELLS) ? cnt[idx+1] : 0;
    int c2 = (idx+2 < NCELLS) ? cnt[idx+2] : 0;
    int c3 = (idx+3 < NCELLS) ? cnt[idx+3] : 0;
    int s0=c0, s1=s0+c1, s2=s1+c2, s3=s2+c3;
    int v = s3;
    int lane = tid & 63, wid = tid >> 6;
    #pragma unroll
    for (int d=1; d<64; d<<=1) {
        int u = __shfl_up(v, d, 64);
        if (lane >= d) v += u;
    }
    __shared__ int wsum[4];
    if (lane == 63) wsum[wid] = v;
    __syncthreads();
    int woff = 0;
    #pragma unroll
    for (int w=0; w<3; w++) if (w < wid) woff += wsum[w];
    int texcl = woff + v - s3;
    if (idx+0 < NCELLS) incl[idx+0] = texcl + s0;
    if (idx+1 < NCELLS) incl[idx+1] = texcl + s1;
    if (idx+2 < NCELLS) incl[idx+2] = texcl + s2;
    if (idx+3 < NCELLS) incl[idx+3] = texcl + s3;
    if (tid == 255) bsum[blockIdx.x] = woff + v;
}

// scan step 2
__global__ void k_scan2(const int* __restrict__ bsum, int* __restrict__ bsx,
                        int* __restrict__ ucount) {
    int lane = threadIdx.x;
    if (lane == 0) *ucount = 0;
    int a = (2*lane   < NB) ? bsum[2*lane]   : 0;
    int b = (2*lane+1 < NB) ? bsum[2*lane+1] : 0;
    int s = a + b;
    int v = s;
    #pragma unroll
    for (int d=1; d<64; d<<=1) {
        int u = __shfl_up(v, d, 64);
        if (lane >= d) v += u;
    }
    int excl = v - s;
    if (2*lane   < NB) bsx[2*lane]   = excl;
    if (2*lane+1 < NB) bsx[2*lane+1] = excl + a;
}

// scan step 3: offsets + cursor + work units (k>0 only; empty cells covered
// by the pooled memset — multi-unit cells atomicAdd and NEED zeroed memory)
__global__ __launch_bounds__(256) void k_scan3(const int* __restrict__ incl, const int* __restrict__ cnt,
                                               const int* __restrict__ bsx, int* __restrict__ offs,
                                               int* __restrict__ cursor,
                                               int* __restrict__ units, int* __restrict__ ucount) {
    int idx = blockIdx.x*1024 + threadIdx.x*4;
    int o = bsx[blockIdx.x];
    #pragma unroll
    for (int j=0;j<4;j++) {
        int cell = idx + j;
        if (cell < NCELLS) {
            int k = cnt[cell];
            int e = o + incl[cell] - k;
            offs[cell] = e;
            cursor[cell] = e;
            if (k > 0) {
                int nu = (k + UNIT-1) / UNIT;
                int ub = atomicAdd(ucount, nu);
                int multi = (nu > 1) ? (1<<17) : 0;
                for (int u=0; u<nu; u++) {
                    int c2 = min(UNIT, k - u*UNIT);
                    units[2*(ub+u)]   = cell | multi | (c2<<18);
                    units[2*(ub+u)+1] = e + u*UNIT;
                }
            }
        }
    }
}

// bucket points: pre-resolved (feat row, depth)
__global__ __launch_bounds__(256) void k_fill(const int* __restrict__ flat, int* __restrict__ cursor,
                                              const float* __restrict__ depth,
                                              int* __restrict__ ordYX, float* __restrict__ ordD) {
    int p = blockIdx.x*256 + threadIdx.x;
    if (p >= NPTS) return;
    int cell = flat[p];
    if (cell < 0) return;
    int pos = atomicAdd(&cursor[cell], 1);
    int n = p / (DD*PIX);
    int yx = p % PIX;
    ordYX[pos] = n*PIX + yx;
    ordD[pos] = depth[p];
}

// gather v3: fp16 featT rows (half the L2 traffic)
__global__ __launch_bounds__(256) void k_gather2(const int* __restrict__ units,
                                                 const int* __restrict__ ucount,
                                                 const int* __restrict__ ordYX,
                                                 const float* __restrict__ ordD,
                                                 const f16* __restrict__ featTh,
                                                 float* __restrict__ pooled) {
    int idx = blockIdx.x*4 + (threadIdx.x >> 6);
    if (idx >= *ucount) return;
    int lane = threadIdx.x & 63;
    int u0 = units[2*idx], base = units[2*idx+1];
    int cell = u0 & 0x1ffff;
    bool multi = (u0 >> 17) & 1;
    int count = u0 >> 18;
    float acc0 = 0.f, acc1 = 0.f;
    bool lo = (lane < 16);
    int i = 0;
    for (; i+2 <= count; i += 2) {
        int y0 = ordYX[base+i], y1 = ordYX[base+i+1];
        float d0 = ordD[base+i], d1 = ordD[base+i+1];
        const f16* f0 = featTh + (size_t)y0*CIMG;
        const f16* f1 = featTh + (size_t)y1*CIMG;
        float a = (float)f0[lane];
        float b = (float)f1[lane];
        float c = lo ? (float)f0[64+lane] : 0.f;
        float d = lo ? (float)f1[64+lane] : 0.f;
        acc0 = fmaf(d0, a, acc0);
        acc0 = fmaf(d1, b, acc0);
        acc1 = fmaf(d0, c, acc1);
        acc1 = fmaf(d1, d, acc1);
    }
    if (i < count) {
        int y0 = ordYX[base+i];
        float d0 = ordD[base+i];
        const f16* f0 = featTh + (size_t)y0*CIMG;
        acc0 = fmaf(d0, (float)f0[lane], acc0);
        if (lo) acc1 = fmaf(d0, (float)f0[64+lane], acc1);
    }
    float* dst = pooled + (size_t)cell*CIMG;
    if (multi) {
        atomicAdd(dst + lane, acc0);
        if (lo) atomicAdd(dst + 64 + lane, acc1);
    } else {
        dst[lane] = acc0;
        if (lo) dst[64 + lane] = acc1;
    }
}

// pooled fp32 -> padded NHWC fp16 [362][362][96]
__global__ __launch_bounds__(256) void k_pool2h(const float* __restrict__ pooled,
                                                f16* __restrict__ pooledH) {
    int gx = blockIdx.x;
    const float* src = pooled + (size_t)gx*360*80;
    for (int e = threadIdx.x; e < 360*80; e += 256) {
        int gy = e / 80, c = e % 80;
        pooledH[((size_t)(gx+1)*DSP1 + (gy+1))*DSC + c] = (f16)src[e];
    }
}

// BEV downsample as fp16 MFMA implicit GEMM (swizzled LDS)
template<int STRIDE, int HINP, int EPI>
__global__ __launch_bounds__(256) void k_ds_mfma(const f16* __restrict__ inH,
                                                 const f16* __restrict__ Wt,
                                                 const float* __restrict__ bn_s,
                                                 const float* __restrict__ bn_t,
                                                 f16* __restrict__ outh,
                                                 float* __restrict__ outf) {
    __shared__ f16 lA[128*32];
    __shared__ f16 lB[80*32];
    int m0 = blockIdx.x * 128;
    int tid = threadIdx.x;
    int wid = tid>>6, lane = tid&63;
    int wm = wid*32;
    int lr = lane&15, quad = lane>>4;
    int swr = ((quad ^ (lr&3))<<3);
    f32x4 acc[2][5] = {};

    int rr = tid >> 1;
    int g0 = tid & 1, g1 = g0 + 2;
    int am = min(m0 + rr, DSM-1);
    int axo = am / 180, ayo = am % 180;
    const f16* arow0 = inH + ((size_t)(axo*STRIDE)*HINP + (size_t)ayo*STRIDE)*DSC;
    const f16* brow0 = Wt + (size_t)rr*288;

    for (int kx=0; kx<3; kx++) {
        const f16* arow = arow0 + (size_t)kx*HINP*DSC;
        const f16* brow = brow0 + (size_t)kx*80*288;
        for (int k0=0; k0<288; k0+=32) {
            *(float4*)(&lA[SWZ(rr,g0)]) = *(const float4*)(arow + k0 + g0*8);
            *(float4*)(&lA[SWZ(rr,g1)]) = *(const float4*)(arow + k0 + g1*8);
            if (tid < 160) {
                *(float4*)(&lB[SWZ(rr,g0)]) = *(const float4*)(brow + k0 + g0*8);
                *(float4*)(&lB[SWZ(rr,g1)]) = *(const float4*)(brow + k0 + g1*8);
            }
            __syncthreads();
            f16x8 af[2], bf[5];
            #pragma unroll
            for (int i=0;i<2;i++) af[i] = *(f16x8*)(&lA[((wm+i*16+lr)<<5) + swr]);
            #pragma unroll
            for (int j=0;j<5;j++) bf[j] = *(f16x8*)(&lB[((j*16+lr)<<5) + swr]);
            #pragma unroll
            for (int i=0;i<2;i++)
                #pragma unroll
                for (int j=0;j<5;j++)
                    acc[i][j] = __builtin_amdgcn_mfma_f32_16x16x32_f16(af[i], bf[j], acc[i][j], 0,0,0);
            __syncthreads();
        }
    }
    #pragma unroll
    for (int j=0;j<5;j++) {
        int n = j*16 + lr;
        float ss = bn_s[n], tt = bn_t[n];
        #pragma unroll
        for (int i=0;i<2;i++) {
            #pragma unroll
            for (int r=0;r<4;r++) {
                int m = m0 + wm + i*16 + quad*4 + r;
                if (m >= DSM) continue;
                float v = fmaxf(fmaf(acc[i][j][r], ss, tt), 0.f);
                if (EPI == 0) {
                    int xo = m / 180, yo = m % 180;
                    outh[((size_t)(xo+1)*DSP2 + (yo+1))*DSC + n] = (f16)v;
                } else {
                    outf[(size_t)n*DSM + m] = v;
                }
            }
        }
    }
}

// ---------------- host launcher ----------------
extern "C" void kernel_launch(void* const* d_in, const int* in_sizes, int n_in,
                              void* d_out, int out_size, void* d_ws, size_t ws_size,
                              hipStream_t stream) {
    const float* x_img  = (const float*)d_in[0];
    const float* dimg   = (const float*)d_in[1];
    const float* c2l_R  = (const float*)d_in[2];
    const float* c2l_t  = (const float*)d_in[3];
    const float* intr   = (const float*)d_in[4];
    const float* prot   = (const float*)d_in[5];
    const float* ptran  = (const float*)d_in[6];
    const float* dt1_w  = (const float*)d_in[7];
    const float* dt1_b  = (const float*)d_in[8];
    const float* dt1_s  = (const float*)d_in[9];
    const float* dt1_t  = (const float*)d_in[10];
    const float* dt2_w  = (const float*)d_in[11];
    const float* dt2_b  = (const float*)d_in[12];
    const float* dt2_s  = (const float*)d_in[13];
    const float* dt2_t  = (const float*)d_in[14];
    const float* dt3_w  = (const float*)d_in[15];
    const float* dt3_b  = (const float*)d_in[16];
    const float* dt3_s  = (const float*)d_in[17];
    const float* dt3_t  = (const float*)d_in[18];
    const float* dn1_w  = (const float*)d_in[19];
    const float* dn1_b  = (const float*)d_in[20];
    const float* dn1_s  = (const float*)d_in[21];
    const float* dn1_t  = (const float*)d_in[22];
    const float* dn2_w  = (const float*)d_in[23];
    const float* dn2_b  = (const float*)d_in[24];
    const float* dn2_s  = (const float*)d_in[25];
    const float* dn2_t  = (const float*)d_in[26];
    const float* dn3_w  = (const float*)d_in[27];
    const float* dn3_b  = (const float*)d_in[28];
    const float* ds1_w  = (const float*)d_in[29];
    const float* ds1_s  = (const float*)d_in[30];
    const float* ds1_t  = (const float*)d_in[31];
    const float* ds2_w  = (const float*)d_in[32];
    const float* ds2_s  = (const float*)d_in[33];
    const float* ds2_t  = (const float*)d_in[34];

    float* ws = (float*)d_ws;
    float* mats   = ws + OFF_MATS;
    f16*   WtDS1  = (f16*)(ws + OFF_WDS1);
    f16*   WtDS2  = (f16*)(ws + OFF_WDS2);
    f16*   WtDT2  = (f16*)(ws + OFF_WDT2);
    f16*   WtDT3  = (f16*)(ws + OFF_WDT3);
    f16*   dNH    = (f16*)(ws + OFF_DNH);
    f16*   h2NH   = (f16*)(ws + OFF_H2NH);
    f16*   Q3     = (f16*)(ws + OFF_Q3);
    float* pooled = ws + OFF_A;
    f16*   Q2     = (f16*)(ws + OFF_Q2);
    f16*   Wt1    = (f16*)(ws + OFF_WT1);
    f16*   Wt2    = (f16*)(ws + OFF_WT2);
    f16*   Wt3h   = (f16*)(ws + OFF_TD3);
    float* f3     = ws + OFF_B;
    int*   cnt    = (int*)(ws + OFF_CNT);
    int*   incl   = (int*)(ws + OFF_INCL);
    int*   offs   = (int*)(ws + OFF_OFFS);
    int*   cursor = (int*)(ws + OFF_CURSOR);
    int*   bsum   = (int*)(ws + OFF_BSUM);
    int*   ucnt   = (int*)(ws + OFF_UCNT);
    int*   bsx    = (int*)(ws + OFF_BSX);
    int*   units  = (int*)(ws + OFF_UNITS);
    f16*   pooledH= (f16*)(ws + OFF_POOLH);
    f16*   bev1H  = (f16*)(ws + OFF_BEV1H);
    float* depth  = ws + OFF_C;
    f16*   Q1     = (f16*)(ws + OFF_Q1);
    f16*   featTh = (f16*)(ws + OFF_FEATT);
    int*   flat   = (int*)(ws + OFF_FLAT);
    int*   ordYX  = (int*)(ws + OFF_ORDYX);
    float* ordD   = ws + OFF_ORDD;
    float* outp   = (float*)d_out;

    // weight prep
    k_cam_mats<<<1, 64, 0, stream>>>(prot, ptran, intr, c2l_R, c2l_t, mats);
    k_wtrans_ds<<<270, 256, 0, stream>>>(ds1_w, WtDS1);
    k_wtrans_ds<<<270, 256, 0, stream>>>(ds2_w, WtDS2);
    k_wtrans_dt2<<<40, 256, 0, stream>>>(dt2_w, WtDT2);
    k_wtrans_dt3<<<200, 256, 0, stream>>>(dt3_w, WtDT3);
    k_prep_b3<<<144, 256, 0, stream>>>(dn3_w, Wt3h);
    k_prep_b<320><<<256, 320, 0, stream>>>(dn1_w, Wt1);
    k_prep_b<256><<<256, 256, 0, stream>>>(dn2_w, Wt2);

    // zero padded NHWC buffers
    hipMemsetAsync(dNH, 0, (size_t)NCAM*DP_R*DP_C*8*sizeof(f16), stream);
    hipMemsetAsync(h2NH, 0, (size_t)NCAM*H2_R*H2_C*32*sizeof(f16), stream);
    hipMemsetAsync(Q1, 0, (size_t)NCAM*MSLAB*320*sizeof(f16), stream);

    // dtransform via MFMA GEMM
    k_prep_d<<<4224, 256, 0, stream>>>(dimg, dt1_w, dt1_b, dt1_s, dt1_t, dNH);
    k_gemm_dt2<<<528, 256, 0, stream>>>(dNH, WtDT2, dt2_b, dt2_s, dt2_t, h2NH);
    k_gemm_dt3<<<132, 256, 0, stream>>>(h2NH, WtDT3, dt3_b, dt3_s, dt3_t, Q1);
    k_prep_a1x<<<dim3(32,NCAM), 256, 0, stream>>>(x_img, Q1);

    // depthnet via MFMA GEMM (swizzled LDS, 128x128)
    hipMemsetAsync(Q2, 0, (size_t)NCAM*MSLAB*256*sizeof(f16), stream);
    k_gemm_conv<320,0><<<dim3(144,2), 256, 0, stream>>>(Q1, Wt1, dn1_b, dn1_s, dn1_t, Q2);
    k_gemm_conv<256,1><<<dim3(144,2), 256, 0, stream>>>(Q2, Wt2, dn2_b, dn2_s, dn2_t, Q3);
    k_gemm_dn3<<<132, 256, 0, stream>>>(Q3, Wt3h, dn3_b, f3);

    // softmax (register single-pass) + featT transpose (fp16)
    k_softmax2<<<66, 256, 0, stream>>>(f3, depth);
    k_featT<<<dim3(32,NCAM), 256, 0, stream>>>(f3, featTh);

    // bev_pool (pooled memset REQUIRED: multi-unit cells atomicAdd)
    hipMemsetAsync(cnt, 0, NCELLS*sizeof(int), stream);
    hipMemsetAsync(pooled, 0, (size_t)NCELLS*CIMG*sizeof(float), stream);
    k_voxel<<<3894, 256, 0, stream>>>(mats, flat, cnt);
    k_scan1<<<NB, 256, 0, stream>>>(cnt, incl, bsum);
    k_scan2<<<1, 64, 0, stream>>>(bsum, bsx, ucnt);
    k_scan3<<<NB, 256, 0, stream>>>(incl, cnt, bsx, offs, cursor, units, ucnt);
    k_fill<<<3894, 256, 0, stream>>>(flat, cursor, depth, ordYX, ordD);
    k_gather2<<<GATHER_BLOCKS, 256, 0, stream>>>(units, ucnt, ordYX, ordD, featTh, pooled);

    // downsample via MFMA GEMM (swizzled)
    hipMemsetAsync(pooledH, 0, (size_t)DSP1*DSP1*DSC*sizeof(f16), stream);
    hipMemsetAsync(bev1H, 0, (size_t)DSP2*DSP2*DSC*sizeof(f16), stream);
    k_pool2h<<<360, 256, 0, stream>>>(pooled, pooledH);
    k_ds_mfma<2,DSP1,0><<<254, 256, 0, stream>>>(pooledH, WtDS1, ds1_s, ds1_t, bev1H, nullptr);
    k_ds_mfma<1,DSP2,1><<<254, 256, 0, stream>>>(bev1H, WtDS2, ds2_s, ds2_t, nullptr, outp);
}

// Round 17
// 657.577 us; speedup vs baseline: 1.0581x; 1.0581x over previous
//
#include <hip/hip_runtime.h>
#include <math.h>

// ---------------- problem constants ----------------
#define NCAM 6
#define IH 256
#define IW 704
#define FH 32
#define FW 88
#define DD 59
#define CIMG 80
#define NXv 360
#define PIX (FH*FW)           // 2816
#define IMGPIX (IH*IW)        // 180224
#define NPTS (NCAM*DD*PIX)    // 996864
#define NCELLS (NXv*NXv)      // 129600
#define NB 127                // scan blocks
#define UNIT 32
#define MAXUNITS (NCELLS + NPTS/UNIT + 1)   // 160753
#define GATHER_BLOCKS ((MAXUNITS + 3) / 4)  // 40189

// padded GEMM pixel space (depthnet): rows [35] x pitch [96]
#define MPITCH 96
#define MROWS  35
#define MSLAB  (MROWS*MPITCH) // 3360

// dtransform NHWC padded buffers
#define DP_R 260
#define DP_C 708
#define H2_R 68
#define H2_C 180

// BEV ds GEMM
#define DSM   32400
#define DSP1  362
#define DSP2  182
#define DSC   96

typedef _Float16 f16;
typedef f16  f16x8 __attribute__((ext_vector_type(8)));
typedef float f32x4 __attribute__((ext_vector_type(4)));

// XOR-swizzled LDS staging (pitch 32 halves)
#define SWZ(r, g) (((r)<<5) + (((g) ^ ((r)&3))<<3))

// ---------------- ws arena offsets (in floats) ----------------
#define OFF_MATS 0                      // 144
#define OFF_WDS1 144                    // 34,560 (3x80x288 fp16)
#define OFF_WDT2 34704                  // 5,120 (5x32x64 fp16)
#define OFF_WDS2 57744                  // 34,560
// SEG_A: {dNH, h2NH} -> {Q3 + Q2 + Wt1 + Wt2 + Wt3h} -> pooled
#define OFF_A    115344
#define OFF_DNH  OFF_A
#define OFF_H2NH (OFF_A + 4416960)
#define OFF_Q3   OFF_A                  // 6x2816x256 fp16 [dn2..dn3]
#define OFF_Q2   (OFF_A + 4325376)
#define OFF_WT1  (OFF_A + 6905856)      // 9x256x320 fp16
#define OFF_WT2  (OFF_A + 7274496)      // 9x256x256 fp16
#define OFF_TD3  (OFF_A + 7569408)      // Wt3h: 144x256 fp16
// SEG_B
#define OFF_B    10483344
#define OFF_CNT    (OFF_B)
#define OFF_INCL   (OFF_B + 131072)
#define OFF_OFFS   (OFF_B + 262144)
#define OFF_CURSOR (OFF_B + 393216)
#define OFF_BSUM   (OFF_B + 524288)
#define OFF_UCNT   (OFF_B + 524480)
#define OFF_BSX    (OFF_B + 524544)
#define OFF_UNITS  (OFF_B + 525312)
#define OFF_POOLH  (OFF_B)
#define OFF_BEV1H  (OFF_B + 6289632)
// SEG_C
#define OFF_C    12831888
// SEG_D
#define OFF_D      13913232
#define OFF_Q1     OFF_D
#define OFF_FEATT  OFF_D                // fp16 [16896][80]
#define OFF_FLAT   (OFF_D + 1351680)
#define OFF_ORDYX  (OFF_D + 2348544)
#define OFF_ORDD   (OFF_D + 3345408)
// total 18,853,776 floats ~75.4 MB

// k_prep_all block ranges
#define PB_DS1 0        // 270 blocks: ds1 weights
#define PB_DS2 270      // 270: ds2 weights
#define PB_DT2 540      // 40: dt2 weights
#define PB_DT3 580      // 200: dt3 weights
#define PB_B3  780      // 144: dn3 weights
#define PB_B1  924      // 320: dn1 weights
#define PB_B2  1244     // 256: dn2 weights
#define PB_CM  1500     // 1: cam mats
#define PB_Z   1501     // 1200: zero dNH/h2NH/Q1
#define PB_TOT 2701
#define ZC0 1104240     // dNH float4 count (4,416,960/4 — stops at OFF_H2NH)
#define ZC1 293760      // h2NH float4 count (1,175,040/4)
#define ZC2 806400      // Q1 float4 count (3,225,600/4)

// ---------------- small helpers ----------------
__device__ __forceinline__ void inv3(const float* m, float* o) {
    float a=m[0],b=m[1],c=m[2],d=m[3],e=m[4],f=m[5],g=m[6],h=m[7],i=m[8];
    float A =  (e*i - f*h);
    float B = -(d*i - f*g);
    float C =  (d*h - e*g);
    float det = a*A + b*B + c*C;
    float r = 1.f/det;
    o[0]=A*r;            o[1]=-(b*i - c*h)*r; o[2]=(b*f - c*e)*r;
    o[3]=B*r;            o[4]=(a*i - c*g)*r;  o[5]=-(a*f - c*d)*r;
    o[6]=C*r;            o[7]=-(a*h - b*g)*r; o[8]=(a*e - b*d)*r;
}

// consolidated prep: all weight transforms + cam mats + early buffer zeroing.
// Pure reorganization of the R16 prep kernels (identical math), 11 launches -> 1.
__global__ __launch_bounds__(256) void k_prep_all(
        const float* __restrict__ prot, const float* __restrict__ ptran,
        const float* __restrict__ intr, const float* __restrict__ Rcl,
        const float* __restrict__ tcl,
        const float* __restrict__ ds1_w, const float* __restrict__ ds2_w,
        const float* __restrict__ dt2_w, const float* __restrict__ dt3_w,
        const float* __restrict__ dn3_w, const float* __restrict__ dn1_w,
        const float* __restrict__ dn2_w,
        float* __restrict__ mats,
        f16* __restrict__ WtDS1, f16* __restrict__ WtDS2,
        f16* __restrict__ WtDT2, f16* __restrict__ WtDT3,
        f16* __restrict__ Wt3h,  f16* __restrict__ Wt1, f16* __restrict__ Wt2,
        float* __restrict__ ws) {
    int rb = blockIdx.x;
    int tid = threadIdx.x;
    if (rb < PB_DS2) {                       // ds1 / ds2 weights
        const float* w = ds1_w; f16* Wt = WtDS1;
        int i = (rb - PB_DS1)*256 + tid;
        if (i < 3*80*288) {
            int k  = i % 288;
            int co = (i / 288) % 80;
            int kx = i / (288*80);
            int ky = k / 96, ci = k % 96;
            Wt[i] = (ci < 80) ? (f16)w[((co*80 + ci)*3 + kx)*3 + ky] : (f16)0.f;
        }
    } else if (rb < PB_DT2) {
        const float* w = ds2_w; f16* Wt = WtDS2;
        int i = (rb - PB_DS2)*256 + tid;
        if (i < 3*80*288) {
            int k  = i % 288;
            int co = (i / 288) % 80;
            int kx = i / (288*80);
            int ky = k / 96, ci = k % 96;
            Wt[i] = (ci < 80) ? (f16)w[((co*80 + ci)*3 + kx)*3 + ky] : (f16)0.f;
        }
    } else if (rb < PB_DT3) {                // dt2 weights
        int i = (rb - PB_DT2)*256 + tid;
        if (i < 5*32*64) {
            int ky = i / (32*64);
            int r  = i % (32*64);
            int co = r / 64;
            int k  = r % 64;
            int kx = k / 8, ci = k % 8;
            WtDT2[i] = (kx < 5) ? (f16)dt2_w[co*200 + ci*25 + ky*5 + kx] : (f16)0.f;
        }
    } else if (rb < PB_B3) {                 // dt3 weights
        int i = (rb - PB_DT3)*256 + tid;
        if (i < 5*64*160) {
            int ky = i / (64*160);
            int r  = i % (64*160);
            int co = r / 160;
            int k  = r % 160;
            int kx = k / 32, ci = k % 32;
            WtDT3[i] = (f16)dt3_w[co*800 + ci*25 + ky*5 + kx];
        }
    } else if (rb < PB_B1) {                 // dn3 weights
        int i = (rb - PB_B3)*256 + tid;
        if (i < 144*256) {
            int co = i / 256;
            Wt3h[i] = (co < 139) ? (f16)dn3_w[i] : (f16)0.f;
        }
    } else if (rb < PB_B2) {                 // dn1 weights [9][256][320]
        int i = (rb - PB_B1)*256 + tid;
        if (i < 256*320) {
            int co = i / 320, ci = i % 320;
            const float* src = dn1_w + ((size_t)co*320 + ci)*9;
            #pragma unroll
            for (int t=0;t<9;t++)
                Wt1[((size_t)t*256 + co)*320 + ci] = (f16)src[t];
        }
    } else if (rb < PB_CM) {                 // dn2 weights [9][256][256]
        int i = (rb - PB_B2)*256 + tid;
        if (i < 256*256) {
            int co = i / 256, ci = i % 256;
            const float* src = dn2_w + ((size_t)co*256 + ci)*9;
            #pragma unroll
            for (int t=0;t<9;t++)
                Wt2[((size_t)t*256 + co)*256 + ci] = (f16)src[t];
        }
    } else if (rb < PB_Z) {                  // cam mats
        int n = tid;
        if (n < NCAM) {
            float P[9], Km[9], R[9], A[9], Ki[9];
            for (int i=0;i<9;i++){ P[i]=prot[n*9+i]; Km[i]=intr[n*9+i]; R[i]=Rcl[n*9+i]; }
            inv3(P, A); inv3(Km, Ki);
            float* M = mats + n*24;
            for (int i=0;i<9;i++) M[i] = A[i];
            for (int r=0;r<3;r++)
                M[9+r] = -(A[r*3+0]*ptran[n*3+0] + A[r*3+1]*ptran[n*3+1] + A[r*3+2]*ptran[n*3+2]);
            for (int r=0;r<3;r++) for (int c=0;c<3;c++)
                M[12 + r*3+c] = R[r*3+0]*Ki[0*3+c] + R[r*3+1]*Ki[1*3+c] + R[r*3+2]*Ki[2*3+c];
            for (int r=0;r<3;r++) M[21+r] = tcl[n*3+r];
        }
    } else {                                 // zero dNH + h2NH + Q1 (grid-stride)
        const float4 z4 = {0.f,0.f,0.f,0.f};
        float4* d0 = (float4*)(ws + OFF_A);
        float4* d1 = (float4*)(ws + OFF_H2NH);
        float4* d2 = (float4*)(ws + OFF_Q1);
        size_t total = (size_t)ZC0 + ZC1 + ZC2;
        size_t stride = (size_t)(PB_TOT - PB_Z)*256;
        for (size_t i = (size_t)(rb - PB_Z)*256 + tid; i < total; i += stride) {
            if (i < ZC0) d0[i] = z4;
            else if (i < (size_t)ZC0 + ZC1) d1[i - ZC0] = z4;
            else d2[i - ZC0 - ZC1] = z4;
        }
    }
}

// fused dt1 -> padded NHWC fp16 [6][260][708][8]
__global__ __launch_bounds__(256) void k_prep_d(const float* __restrict__ d,
                                                const float* __restrict__ w,
                                                const float* __restrict__ b,
                                                const float* __restrict__ s,
                                                const float* __restrict__ t,
                                                f16* __restrict__ dNH) {
    int i = blockIdx.x*256 + threadIdx.x;
    int cam = i / IMGPIX;
    int yx = i % IMGPIX;
    int y = yx / IW, x = yx % IW;
    float v = d[i];
    f16* dst = dNH + ((size_t)cam*DP_R + (y+2))*DP_C*8 + (size_t)(x+2)*8;
    #pragma unroll
    for (int c=0;c<8;c++)
        dst[c] = (f16)fmaxf(fmaf(fmaf(v, w[c], b[c]), s[c], t[c]), 0.f);
}

// dt2 as implicit GEMM (swizzled LDS)
__global__ __launch_bounds__(256) void k_gemm_dt2(const f16* __restrict__ dNH,
                                                  const f16* __restrict__ Wt,
                                                  const float* __restrict__ bias,
                                                  const float* __restrict__ bn_s,
                                                  const float* __restrict__ bn_t,
                                                  f16* __restrict__ h2NH) {
    __shared__ f16 lA[128*32];
    __shared__ f16 lB[32*32];
    int cam = blockIdx.x / 88, mt = blockIdx.x % 88;
    int m0 = mt*128;
    int tid = threadIdx.x;
    int wid = tid>>6, lane = tid&63;
    int wm = wid*32;
    int lr = lane&15, quad = lane>>4;
    int swr = ((quad ^ (lr&3))<<3);
    f32x4 acc[2][2] = {};

    int rr = tid >> 1;
    int g0 = tid & 1, g1 = g0 + 2;
    int am = m0 + rr;
    int ay = am / 176, ax = am % 176;
    const f16* abase = dNH + (size_t)cam*DP_R*DP_C*8 + (size_t)(ay*4)*DP_C*8 + (size_t)(ax*4)*8;

    for (int ky=0; ky<5; ky++) {
        const f16* arow = abase + (size_t)ky*DP_C*8;
        const f16* brow = Wt + ((size_t)ky*32 + rr)*64;
        #pragma unroll
        for (int k0=0; k0<64; k0+=32) {
            *(float4*)(&lA[SWZ(rr,g0)]) = *(const float4*)(arow + k0 + g0*8);
            *(float4*)(&lA[SWZ(rr,g1)]) = *(const float4*)(arow + k0 + g1*8);
            if (tid < 64) {
                *(float4*)(&lB[SWZ(rr,g0)]) = *(const float4*)(brow + k0 + g0*8);
                *(float4*)(&lB[SWZ(rr,g1)]) = *(const float4*)(brow + k0 + g1*8);
            }
            __syncthreads();
            f16x8 af[2], bf[2];
            #pragma unroll
            for (int i=0;i<2;i++) af[i] = *(f16x8*)(&lA[((wm+i*16+lr)<<5) + swr]);
            #pragma unroll
            for (int j=0;j<2;j++) bf[j] = *(f16x8*)(&lB[((j*16+lr)<<5) + swr]);
            #pragma unroll
            for (int i=0;i<2;i++)
                #pragma unroll
                for (int j=0;j<2;j++)
                    acc[i][j] = __builtin_amdgcn_mfma_f32_16x16x32_f16(af[i], bf[j], acc[i][j], 0,0,0);
            __syncthreads();
        }
    }
    #pragma unroll
    for (int j=0;j<2;j++) {
        int n = j*16 + lr;
        float bb = bias[n], ss = bn_s[n], tt = bn_t[n];
        #pragma unroll
        for (int i=0;i<2;i++) {
            #pragma unroll
            for (int r=0;r<4;r++) {
                int m = m0 + wm + i*16 + quad*4 + r;
                int y = m / 176, x = m % 176;
                float v = fmaxf(fmaf(acc[i][j][r] + bb, ss, tt), 0.f);
                h2NH[((size_t)cam*H2_R + (y+2))*H2_C*32 + (size_t)(x+2)*32 + n] = (f16)v;
            }
        }
    }
}

// dt3 as implicit GEMM -> Q1 ch 0..63 (swizzled LDS)
__global__ __launch_bounds__(256) void k_gemm_dt3(const f16* __restrict__ h2NH,
                                                  const f16* __restrict__ Wt,
                                                  const float* __restrict__ bias,
                                                  const float* __restrict__ bn_s,
                                                  const float* __restrict__ bn_t,
                                                  f16* __restrict__ Q1) {
    __shared__ f16 lA[128*32];
    __shared__ f16 lB[64*32];
    int cam = blockIdx.x / 22, mt = blockIdx.x % 22;
    int m0 = mt*128;
    int tid = threadIdx.x;
    int wid = tid>>6, lane = tid&63;
    int wm = wid*32;
    int lr = lane&15, quad = lane>>4;
    int swr = ((quad ^ (lr&3))<<3);
    f32x4 acc[2][4] = {};

    int rr = tid >> 1;
    int g0 = tid & 1, g1 = g0 + 2;
    int am = m0 + rr;
    int ay = am / FW, ax = am % FW;
    const f16* abase = h2NH + (size_t)cam*H2_R*H2_C*32 + (size_t)(ay*2)*H2_C*32 + (size_t)(ax*2)*32;

    for (int ky=0; ky<5; ky++) {
        const f16* arow = abase + (size_t)ky*H2_C*32;
        const f16* brow = Wt + ((size_t)ky*64 + rr)*160;
        #pragma unroll
        for (int k0=0; k0<160; k0+=32) {
            *(float4*)(&lA[SWZ(rr,g0)]) = *(const float4*)(arow + k0 + g0*8);
            *(float4*)(&lA[SWZ(rr,g1)]) = *(const float4*)(arow + k0 + g1*8);
            if (tid < 128) {
                *(float4*)(&lB[SWZ(rr,g0)]) = *(const float4*)(brow + k0 + g0*8);
                *(float4*)(&lB[SWZ(rr,g1)]) = *(const float4*)(brow + k0 + g1*8);
            }
            __syncthreads();
            f16x8 af[2], bf[4];
            #pragma unroll
            for (int i=0;i<2;i++) af[i] = *(f16x8*)(&lA[((wm+i*16+lr)<<5) + swr]);
            #pragma unroll
            for (int j=0;j<4;j++) bf[j] = *(f16x8*)(&lB[((j*16+lr)<<5) + swr]);
            #pragma unroll
            for (int i=0;i<2;i++)
                #pragma unroll
                for (int j=0;j<4;j++)
                    acc[i][j] = __builtin_amdgcn_mfma_f32_16x16x32_f16(af[i], bf[j], acc[i][j], 0,0,0);
            __syncthreads();
        }
    }
    #pragma unroll
    for (int j=0;j<4;j++) {
        int n = j*16 + lr;
        float bb = bias[n], ss = bn_s[n], tt = bn_t[n];
        #pragma unroll
        for (int i=0;i<2;i++) {
            #pragma unroll
            for (int r=0;r<4;r++) {
                int m = m0 + wm + i*16 + quad*4 + r;
                int y = m / FW, x = m % FW;
                float v = fmaxf(fmaf(acc[i][j][r] + bb, ss, tt), 0.f);
                Q1[((size_t)cam*MSLAB + (size_t)(y+1)*MPITCH + (x+1))*320 + n] = (f16)v;
            }
        }
    }
}

// copy x_img -> Q1 channels 64..319
__global__ __launch_bounds__(256) void k_prep_a1x(const float* __restrict__ x_img,
                                                  f16* __restrict__ Q1) {
    __shared__ f16 tile[88*260];
    int y = blockIdx.x, cam = blockIdx.y;
    for (int e = threadIdx.x; e < 88*256; e += 256) {
        int c = e / 88, p = e % 88;
        tile[p*260 + c] = (f16)x_img[((size_t)cam*256 + c)*PIX + y*FW + p];
    }
    __syncthreads();
    f16* dst = Q1 + (size_t)cam*(MSLAB*320) + ((size_t)(y+1)*MPITCH + 1)*320 + 64;
    for (int e = threadIdx.x; e < 88*256; e += 256) {
        int p = e / 256, c = e % 256;
        dst[(size_t)p*320 + c] = tile[p*260 + c];
    }
}

// fp16 implicit-GEMM 3x3 conv (depthnet, swizzled LDS, 128x128)
template<int KCI, int EPI>
__global__ __launch_bounds__(256) void k_gemm_conv(const f16* __restrict__ Aq,
                                                   const f16* __restrict__ Wt,
                                                   const float* __restrict__ bias,
                                                   const float* __restrict__ bn_s,
                                                   const float* __restrict__ bn_t,
                                                   f16* __restrict__ outh) {
    __shared__ f16 lA[128*32];
    __shared__ f16 lB[128*32];
    int cam = blockIdx.x / 24, mt = blockIdx.x % 24;
    int m0 = mt*128;
    int co0 = blockIdx.y * 128;
    int tid = threadIdx.x;
    f32x4 acc[4][4] = {};
    const f16* Abase = Aq + (size_t)cam*MSLAB*KCI;
    int rr = tid >> 1;
    int g0 = tid & 1, g1 = g0 + 2;
    int wid = tid>>6, lane = tid&63;
    int wm = (wid&1)*64, wn = (wid>>1)*64;
    int lr = lane&15, quad = lane>>4;
    int swr = ((quad ^ (lr&3))<<3);

    for (int t=0; t<9; t++) {
        int moff = (t/3)*MPITCH + (t%3);
        const f16* At = Abase + (size_t)(m0 + moff + rr)*KCI;
        const f16* Bt = Wt + ((size_t)t*256 + co0 + rr)*KCI;
        for (int k0=0; k0<KCI; k0+=32) {
            *(float4*)(&lA[SWZ(rr,g0)]) = *(const float4*)(At + k0 + g0*8);
            *(float4*)(&lA[SWZ(rr,g1)]) = *(const float4*)(At + k0 + g1*8);
            *(float4*)(&lB[SWZ(rr,g0)]) = *(const float4*)(Bt + k0 + g0*8);
            *(float4*)(&lB[SWZ(rr,g1)]) = *(const float4*)(Bt + k0 + g1*8);
            __syncthreads();
            f16x8 af[4], bf[4];
            #pragma unroll
            for (int i=0;i<4;i++) af[i] = *(f16x8*)(&lA[((wm+i*16+lr)<<5) + swr]);
            #pragma unroll
            for (int j=0;j<4;j++) bf[j] = *(f16x8*)(&lB[((wn+j*16+lr)<<5) + swr]);
            #pragma unroll
            for (int i=0;i<4;i++)
                #pragma unroll
                for (int j=0;j<4;j++)
                    acc[i][j] = __builtin_amdgcn_mfma_f32_16x16x32_f16(af[i], bf[j], acc[i][j], 0,0,0);
            __syncthreads();
        }
    }
    #pragma unroll
    for (int j=0;j<4;j++) {
        int n = co0 + wn + j*16 + lr;
        float bb = bias[n], ss = bn_s[n], tt = bn_t[n];
        #pragma unroll
        for (int i=0;i<4;i++) {
            #pragma unroll
            for (int r=0;r<4;r++) {
                int m = m0 + wm + i*16 + quad*4 + r;
                int y = m / MPITCH, x = m % MPITCH;
                if (x >= FW || y >= FH) continue;
                float v = fmaxf(fmaf(acc[i][j][r] + bb, ss, tt), 0.f);
                if (EPI == 0)
                    outh[((size_t)cam*MSLAB + (size_t)(y+1)*MPITCH + (x+1))*256 + n] = (f16)v;
                else
                    outh[((size_t)cam*PIX + (size_t)(y*FW + x))*256 + n] = (f16)v;
            }
        }
    }
}

// dn3 as MFMA GEMM (M=2816/cam, N=144, K=256) -> f3 fp32 NCHW
__global__ __launch_bounds__(256) void k_gemm_dn3(const f16* __restrict__ Q3,
                                                  const f16* __restrict__ Wt,
                                                  const float* __restrict__ bias,
                                                  float* __restrict__ f3) {
    __shared__ f16 lA[128*32];
    __shared__ f16 lB[144*32];
    int cam = blockIdx.x / 22, mt = blockIdx.x % 22;
    int m0 = mt*128;
    int tid = threadIdx.x;
    int wid = tid>>6, lane = tid&63;
    int wm = wid*32;
    int lr = lane&15, quad = lane>>4;
    int swr = ((quad ^ (lr&3))<<3);
    f32x4 acc[2][9] = {};

    int rr = tid >> 1;
    int g0 = tid & 1, g1 = g0 + 2;
    const f16* abase = Q3 + ((size_t)cam*PIX + m0 + rr)*256;
    const f16* bbase = Wt + (size_t)tid*256;

    for (int k0=0; k0<256; k0+=32) {
        *(float4*)(&lA[SWZ(rr,g0)]) = *(const float4*)(abase + k0 + g0*8);
        *(float4*)(&lA[SWZ(rr,g1)]) = *(const float4*)(abase + k0 + g1*8);
        if (tid < 144) {
            #pragma unroll
            for (int g=0; g<4; g++)
                *(float4*)(&lB[SWZ(tid,g)]) = *(const float4*)(bbase + k0 + g*8);
        }
        __syncthreads();
        f16x8 af[2], bf[9];
        #pragma unroll
        for (int i=0;i<2;i++) af[i] = *(f16x8*)(&lA[((wm+i*16+lr)<<5) + swr]);
        #pragma unroll
        for (int j=0;j<9;j++) bf[j] = *(f16x8*)(&lB[((j*16+lr)<<5) + swr]);
        #pragma unroll
        for (int i=0;i<2;i++)
            #pragma unroll
            for (int j=0;j<9;j++)
                acc[i][j] = __builtin_amdgcn_mfma_f32_16x16x32_f16(af[i], bf[j], acc[i][j], 0,0,0);
        __syncthreads();
    }
    #pragma unroll
    for (int j=0;j<9;j++) {
        int n = j*16 + lr;
        if (n >= 139) continue;
        float bb = bias[n];
        #pragma unroll
        for (int i=0;i<2;i++) {
            #pragma unroll
            for (int r=0;r<4;r++) {
                int m = m0 + wm + i*16 + quad*4 + r;
                f3[((size_t)cam*139 + n)*PIX + m] = acc[i][j][r] + bb;
            }
        }
    }
}

// softmax v2: register-cached single pass over the 59 depth logits
__global__ __launch_bounds__(256) void k_softmax2(const float* __restrict__ f3,
                                                  float* __restrict__ depth) {
    int o = blockIdx.x*256 + threadIdx.x;       // 16896
    int n = o / PIX, yx = o % PIX;
    const float* fp = f3 + (size_t)n*139*PIX + yx;
    float r[DD];
    #pragma unroll
    for (int d=0; d<DD; d++) r[d] = fp[(size_t)d*PIX];
    float m = -1e30f;
    #pragma unroll
    for (int d=0; d<DD; d++) m = fmaxf(m, r[d]);
    float sum = 0.f;
    #pragma unroll
    for (int d=0; d<DD; d++) { r[d] = expf(r[d]-m); sum += r[d]; }
    float inv = 1.f/sum;
    #pragma unroll
    for (int d=0; d<DD; d++)
        depth[((size_t)n*DD+d)*PIX + yx] = r[d]*inv;
}

// featT transpose: f3 ch 59..138 -> fp16 [n*PIX+yx][80], LDS-tiled
__global__ __launch_bounds__(256) void k_featT(const float* __restrict__ f3,
                                               f16* __restrict__ featTh) {
    __shared__ float tile[88*81];
    int y = blockIdx.x, cam = blockIdx.y;
    const float* src = f3 + (size_t)cam*139*PIX + (size_t)DD*PIX + y*FW;
    for (int e = threadIdx.x; e < 88*80; e += 256) {
        int c = e / 88, p = e % 88;
        tile[p*81 + c] = src[(size_t)c*PIX + p];
    }
    __syncthreads();
    f16* dst = featTh + ((size_t)cam*PIX + y*FW)*CIMG;
    for (int e = threadIdx.x; e < 88*80; e += 256) {
        int p = e / 80, c = e % 80;
        dst[(size_t)p*CIMG + c] = (f16)tile[p*81 + c];
    }
}

// frustum -> voxel index + histogram
__global__ __launch_bounds__(256) void k_voxel(const float* __restrict__ mats, int* __restrict__ flat,
                                               int* __restrict__ cnt) {
    int p = blockIdx.x*256 + threadIdx.x;
    if (p >= NPTS) return;
    int x = p % FW; int t1 = p / FW;
    int y = t1 % FH; int t2 = t1 / FH;
    int dd = t2 % DD; int n = t2 / DD;
    float xf = x * (703.f/87.f);
    float yf = y * (255.f/31.f);
    float df = 1.f + (float)dd;
    const float* M = mats + n*24;
    float qx = M[0]*xf + M[1]*yf + M[2]*df + M[9];
    float qy = M[3]*xf + M[4]*yf + M[5]*df + M[10];
    float qz = M[6]*xf + M[7]*yf + M[8]*df + M[11];
    float rx = qx*qz, ry = qy*qz, rz = qz;
    float wx = M[12]*rx + M[13]*ry + M[14]*rz + M[21];
    float wy = M[15]*rx + M[16]*ry + M[17]*rz + M[22];
    float wz = M[18]*rx + M[19]*ry + M[20]*rz + M[23];
    int gx = (int)((wx + 54.f) / 0.3f);
    int gy = (int)((wy + 54.f) / 0.3f);
    int gz = (int)((wz + 10.f) / 20.f);
    bool kept = ((unsigned)gx < NXv) && ((unsigned)gy < NXv) && (gz == 0);
    int cell = kept ? (gx*NXv + gy) : -1;
    flat[p] = cell;
    if (kept) atomicAdd(&cnt[cell], 1);
}

// scan step 1
__global__ __launch_bounds__(256) void k_scan1(const int* __restrict__ cnt, int* __restrict__ incl,
                                               int* __restrict__ bsum) {
    int tid = threadIdx.x;
    int idx = blockIdx.x*1024 + tid*4;
    int c0 = (idx+0 < NCELLS) ? cnt[idx+0] : 0;
    int c1 = (idx+1 < NCELLS) ? cnt[idx+1] : 0;
    int c2 = (idx+2 < NCELLS) ? cnt[idx+2] : 0;
    int c3 = (idx+3 < NCELLS) ? cnt[idx+3] : 0;
    int s0=c0, s1=s0+c1, s2=s1+c2, s3=s2+c3;
    int v = s3;
    int lane = tid & 63, wid = tid >> 6;
    #pragma unroll
    for (int d=1; d<64; d<<=1) {
        int u = __shfl_up(v, d, 64);
        if (lane >= d) v += u;
    }
    __shared__ int wsum[4];
    if (lane == 63) wsum[wid] = v;
    __syncthreads();
    int woff = 0;
    #pragma unroll
    for (int w=0; w<3; w++) if (w < wid) woff += wsum[w];
    int texcl = woff + v - s3;
    if (idx+0 < NCELLS) incl[idx+0] = texcl + s0;
    if (idx+1 < NCELLS) incl[idx+1] = texcl + s1;
    if (idx+2 < NCELLS) incl[idx+2] = texcl + s2;
    if (idx+3 < NCELLS) incl[idx+3] = texcl + s3;
    if (tid == 255) bsum[blockIdx.x] = woff + v;
}

// scan step 2
__global__ void k_scan2(const int* __restrict__ bsum, int* __restrict__ bsx,
                        int* __restrict__ ucount) {
    int lane = threadIdx.x;
    if (lane == 0) *ucount = 0;
    int a = (2*lane   < NB) ? bsum[2*lane]   : 0;
    int b = (2*lane+1 < NB) ? bsum[2*lane+1] : 0;
    int s = a + b;
    int v = s;
    #pragma unroll
    for (int d=1; d<64; d<<=1) {
        int u = __shfl_up(v, d, 64);
        if (lane >= d) v += u;
    }
    int excl = v - s;
    if (2*lane   < NB) bsx[2*lane]   = excl;
    if (2*lane+1 < NB) bsx[2*lane+1] = excl + a;
}

// scan step 3: offsets + cursor + work units (k>0 only)
__global__ __launch_bounds__(256) void k_scan3(const int* __restrict__ incl, const int* __restrict__ cnt,
                                               const int* __restrict__ bsx, int* __restrict__ offs,
                                               int* __restrict__ cursor,
                                               int* __restrict__ units, int* __restrict__ ucount) {
    int idx = blockIdx.x*1024 + threadIdx.x*4;
    int o = bsx[blockIdx.x];
    #pragma unroll
    for (int j=0;j<4;j++) {
        int cell = idx + j;
        if (cell < NCELLS) {
            int k = cnt[cell];
            int e = o + incl[cell] - k;
            offs[cell] = e;
            cursor[cell] = e;
            if (k > 0) {
                int nu = (k + UNIT-1) / UNIT;
                int ub = atomicAdd(ucount, nu);
                int multi = (nu > 1) ? (1<<17) : 0;
                for (int u=0; u<nu; u++) {
                    int c2 = min(UNIT, k - u*UNIT);
                    units[2*(ub+u)]   = cell | multi | (c2<<18);
                    units[2*(ub+u)+1] = e + u*UNIT;
                }
            }
        }
    }
}

// bucket points: pre-resolved (feat row, depth)
__global__ __launch_bounds__(256) void k_fill(const int* __restrict__ flat, int* __restrict__ cursor,
                                              const float* __restrict__ depth,
                                              int* __restrict__ ordYX, float* __restrict__ ordD) {
    int p = blockIdx.x*256 + threadIdx.x;
    if (p >= NPTS) return;
    int cell = flat[p];
    if (cell < 0) return;
    int pos = atomicAdd(&cursor[cell], 1);
    int n = p / (DD*PIX);
    int yx = p % PIX;
    ordYX[pos] = n*PIX + yx;
    ordD[pos] = depth[p];
}

// gather v3: fp16 featT rows
__global__ __launch_bounds__(256) void k_gather2(const int* __restrict__ units,
                                                 const int* __restrict__ ucount,
                                                 const int* __restrict__ ordYX,
                                                 const float* __restrict__ ordD,
                                                 const f16* __restrict__ featTh,
                                                 float* __restrict__ pooled) {
    int idx = blockIdx.x*4 + (threadIdx.x >> 6);
    if (idx >= *ucount) return;
    int lane = threadIdx.x & 63;
    int u0 = units[2*idx], base = units[2*idx+1];
    int cell = u0 & 0x1ffff;
    bool multi = (u0 >> 17) & 1;
    int count = u0 >> 18;
    float acc0 = 0.f, acc1 = 0.f;
    bool lo = (lane < 16);
    int i = 0;
    for (; i+2 <= count; i += 2) {
        int y0 = ordYX[base+i], y1 = ordYX[base+i+1];
        float d0 = ordD[base+i], d1 = ordD[base+i+1];
        const f16* f0 = featTh + (size_t)y0*CIMG;
        const f16* f1 = featTh + (size_t)y1*CIMG;
        float a = (float)f0[lane];
        float b = (float)f1[lane];
        float c = lo ? (float)f0[64+lane] : 0.f;
        float d = lo ? (float)f1[64+lane] : 0.f;
        acc0 = fmaf(d0, a, acc0);
        acc0 = fmaf(d1, b, acc0);
        acc1 = fmaf(d0, c, acc1);
        acc1 = fmaf(d1, d, acc1);
    }
    if (i < count) {
        int y0 = ordYX[base+i];
        float d0 = ordD[base+i];
        const f16* f0 = featTh + (size_t)y0*CIMG;
        acc0 = fmaf(d0, (float)f0[lane], acc0);
        if (lo) acc1 = fmaf(d0, (float)f0[64+lane], acc1);
    }
    float* dst = pooled + (size_t)cell*CIMG;
    if (multi) {
        atomicAdd(dst + lane, acc0);
        if (lo) atomicAdd(dst + 64 + lane, acc1);
    } else {
        dst[lane] = acc0;
        if (lo) dst[64 + lane] = acc1;
    }
}

// pooled fp32 -> padded NHWC fp16 [362][362][96]
__global__ __launch_bounds__(256) void k_pool2h(const float* __restrict__ pooled,
                                                f16* __restrict__ pooledH) {
    int gx = blockIdx.x;
    const float* src = pooled + (size_t)gx*360*80;
    for (int e = threadIdx.x; e < 360*80; e += 256) {
        int gy = e / 80, c = e % 80;
        pooledH[((size_t)(gx+1)*DSP1 + (gy+1))*DSC + c] = (f16)src[e];
    }
}

// BEV downsample as fp16 MFMA implicit GEMM (swizzled LDS)
template<int STRIDE, int HINP, int EPI>
__global__ __launch_bounds__(256) void k_ds_mfma(const f16* __restrict__ inH,
                                                 const f16* __restrict__ Wt,
                                                 const float* __restrict__ bn_s,
                                                 const float* __restrict__ bn_t,
                                                 f16* __restrict__ outh,
                                                 float* __restrict__ outf) {
    __shared__ f16 lA[128*32];
    __shared__ f16 lB[80*32];
    int m0 = blockIdx.x * 128;
    int tid = threadIdx.x;
    int wid = tid>>6, lane = tid&63;
    int wm = wid*32;
    int lr = lane&15, quad = lane>>4;
    int swr = ((quad ^ (lr&3))<<3);
    f32x4 acc[2][5] = {};

    int rr = tid >> 1;
    int g0 = tid & 1, g1 = g0 + 2;
    int am = min(m0 + rr, DSM-1);
    int axo = am / 180, ayo = am % 180;
    const f16* arow0 = inH + ((size_t)(axo*STRIDE)*HINP + (size_t)ayo*STRIDE)*DSC;
    const f16* brow0 = Wt + (size_t)rr*288;

    for (int kx=0; kx<3; kx++) {
        const f16* arow = arow0 + (size_t)kx*HINP*DSC;
        const f16* brow = brow0 + (size_t)kx*80*288;
        for (int k0=0; k0<288; k0+=32) {
            *(float4*)(&lA[SWZ(rr,g0)]) = *(const float4*)(arow + k0 + g0*8);
            *(float4*)(&lA[SWZ(rr,g1)]) = *(const float4*)(arow + k0 + g1*8);
            if (tid < 160) {
                *(float4*)(&lB[SWZ(rr,g0)]) = *(const float4*)(brow + k0 + g0*8);
                *(float4*)(&lB[SWZ(rr,g1)]) = *(const float4*)(brow + k0 + g1*8);
            }
            __syncthreads();
            f16x8 af[2], bf[5];
            #pragma unroll
            for (int i=0;i<2;i++) af[i] = *(f16x8*)(&lA[((wm+i*16+lr)<<5) + swr]);
            #pragma unroll
            for (int j=0;j<5;j++) bf[j] = *(f16x8*)(&lB[((j*16+lr)<<5) + swr]);
            #pragma unroll
            for (int i=0;i<2;i++)
                #pragma unroll
                for (int j=0;j<5;j++)
                    acc[i][j] = __builtin_amdgcn_mfma_f32_16x16x32_f16(af[i], bf[j], acc[i][j], 0,0,0);
            __syncthreads();
        }
    }
    #pragma unroll
    for (int j=0;j<5;j++) {
        int n = j*16 + lr;
        float ss = bn_s[n], tt = bn_t[n];
        #pragma unroll
        for (int i=0;i<2;i++) {
            #pragma unroll
            for (int r=0;r<4;r++) {
                int m = m0 + wm + i*16 + quad*4 + r;
                if (m >= DSM) continue;
                float v = fmaxf(fmaf(acc[i][j][r], ss, tt), 0.f);
                if (EPI == 0) {
                    int xo = m / 180, yo = m % 180;
                    outh[((size_t)(xo+1)*DSP2 + (yo+1))*DSC + n] = (f16)v;
                } else {
                    outf[(size_t)n*DSM + m] = v;
                }
            }
        }
    }
}

// ---------------- host launcher ----------------
extern "C" void kernel_launch(void* const* d_in, const int* in_sizes, int n_in,
                              void* d_out, int out_size, void* d_ws, size_t ws_size,
                              hipStream_t stream) {
    const float* x_img  = (const float*)d_in[0];
    const float* dimg   = (const float*)d_in[1];
    const float* c2l_R  = (const float*)d_in[2];
    const float* c2l_t  = (const float*)d_in[3];
    const float* intr   = (const float*)d_in[4];
    const float* prot   = (const float*)d_in[5];
    const float* ptran  = (const float*)d_in[6];
    const float* dt1_w  = (const float*)d_in[7];
    const float* dt1_b  = (const float*)d_in[8];
    const float* dt1_s  = (const float*)d_in[9];
    const float* dt1_t  = (const float*)d_in[10];
    const float* dt2_w  = (const float*)d_in[11];
    const float* dt2_b  = (const float*)d_in[12];
    const float* dt2_s  = (const float*)d_in[13];
    const float* dt2_t  = (const float*)d_in[14];
    const float* dt3_w  = (const float*)d_in[15];
    const float* dt3_b  = (const float*)d_in[16];
    const float* dt3_s  = (const float*)d_in[17];
    const float* dt3_t  = (const float*)d_in[18];
    const float* dn1_w  = (const float*)d_in[19];
    const float* dn1_b  = (const float*)d_in[20];
    const float* dn1_s  = (const float*)d_in[21];
    const float* dn1_t  = (const float*)d_in[22];
    const float* dn2_w  = (const float*)d_in[23];
    const float* dn2_b  = (const float*)d_in[24];
    const float* dn2_s  = (const float*)d_in[25];
    const float* dn2_t  = (const float*)d_in[26];
    const float* dn3_w  = (const float*)d_in[27];
    const float* dn3_b  = (const float*)d_in[28];
    const float* ds1_w  = (const float*)d_in[29];
    const float* ds1_s  = (const float*)d_in[30];
    const float* ds1_t  = (const float*)d_in[31];
    const float* ds2_w  = (const float*)d_in[32];
    const float* ds2_s  = (const float*)d_in[33];
    const float* ds2_t  = (const float*)d_in[34];

    float* ws = (float*)d_ws;
    float* mats   = ws + OFF_MATS;
    f16*   WtDS1  = (f16*)(ws + OFF_WDS1);
    f16*   WtDS2  = (f16*)(ws + OFF_WDS2);
    f16*   WtDT2  = (f16*)(ws + OFF_WDT2);
    f16*   WtDT3  = (f16*)(ws + OFF_B);      // dead scratch until scan; same slot as before
    f16*   dNH    = (f16*)(ws + OFF_DNH);
    f16*   h2NH   = (f16*)(ws + OFF_H2NH);
    f16*   Q3     = (f16*)(ws + OFF_Q3);
    float* pooled = ws + OFF_A;
    f16*   Q2     = (f16*)(ws + OFF_Q2);
    f16*   Wt1    = (f16*)(ws + OFF_WT1);
    f16*   Wt2    = (f16*)(ws + OFF_WT2);
    f16*   Wt3h   = (f16*)(ws + OFF_TD3);
    float* f3     = ws + OFF_B;
    int*   cnt    = (int*)(ws + OFF_CNT);
    int*   incl   = (int*)(ws + OFF_INCL);
    int*   offs   = (int*)(ws + OFF_OFFS);
    int*   cursor = (int*)(ws + OFF_CURSOR);
    int*   bsum   = (int*)(ws + OFF_BSUM);
    int*   ucnt   = (int*)(ws + OFF_UCNT);
    int*   bsx    = (int*)(ws + OFF_BSX);
    int*   units  = (int*)(ws + OFF_UNITS);
    f16*   pooledH= (f16*)(ws + OFF_POOLH);
    f16*   bev1H  = (f16*)(ws + OFF_BEV1H);
    float* depth  = ws + OFF_C;
    f16*   Q1     = (f16*)(ws + OFF_Q1);
    f16*   featTh = (f16*)(ws + OFF_FEATT);
    int*   flat   = (int*)(ws + OFF_FLAT);
    int*   ordYX  = (int*)(ws + OFF_ORDYX);
    float* ordD   = ws + OFF_ORDD;
    float* outp   = (float*)d_out;

    // NOTE: WtDT3 lives at OFF_B (f3/scan territory) — it is consumed by
    // k_gemm_dt3 which runs BEFORE dn3 writes f3 there. Same lifetime as R16.

    // consolidated prep: all weight transforms + cam mats + dNH/h2NH/Q1 zeroing
    k_prep_all<<<PB_TOT, 256, 0, stream>>>(prot, ptran, intr, c2l_R, c2l_t,
                                           ds1_w, ds2_w, dt2_w, dt3_w, dn3_w, dn1_w, dn2_w,
                                           mats, WtDS1, WtDS2, WtDT2, WtDT3, Wt3h, Wt1, Wt2, ws);

    // dtransform via MFMA GEMM
    k_prep_d<<<4224, 256, 0, stream>>>(dimg, dt1_w, dt1_b, dt1_s, dt1_t, dNH);
    k_gemm_dt2<<<528, 256, 0, stream>>>(dNH, WtDT2, dt2_b, dt2_s, dt2_t, h2NH);
    k_gemm_dt3<<<132, 256, 0, stream>>>(h2NH, WtDT3, dt3_b, dt3_s, dt3_t, Q1);
    k_prep_a1x<<<dim3(32,NCAM), 256, 0, stream>>>(x_img, Q1);

    // depthnet via MFMA GEMM (swizzled LDS, 128x128)
    hipMemsetAsync(Q2, 0, (size_t)NCAM*MSLAB*256*sizeof(f16), stream);
    k_gemm_conv<320,0><<<dim3(144,2), 256, 0, stream>>>(Q1, Wt1, dn1_b, dn1_s, dn1_t, Q2);
    k_gemm_conv<256,1><<<dim3(144,2), 256, 0, stream>>>(Q2, Wt2, dn2_b, dn2_s, dn2_t, Q3);
    k_gemm_dn3<<<132, 256, 0, stream>>>(Q3, Wt3h, dn3_b, f3);

    // softmax (register single-pass) + featT transpose (fp16)
    k_softmax2<<<66, 256, 0, stream>>>(f3, depth);
    k_featT<<<dim3(32,NCAM), 256, 0, stream>>>(f3, featTh);

    // bev_pool (pooled memset REQUIRED: multi-unit cells atomicAdd)
    hipMemsetAsync(cnt, 0, NCELLS*sizeof(int), stream);
    hipMemsetAsync(pooled, 0, (size_t)NCELLS*CIMG*sizeof(float), stream);
    k_voxel<<<3894, 256, 0, stream>>>(mats, flat, cnt);
    k_scan1<<<NB, 256, 0, stream>>>(cnt, incl, bsum);
    k_scan2<<<1, 64, 0, stream>>>(bsum, bsx, ucnt);
    k_scan3<<<NB, 256, 0, stream>>>(incl, cnt, bsx, offs, cursor, units, ucnt);
    k_fill<<<3894, 256, 0, stream>>>(flat, cursor, depth, ordYX, ordD);
    k_gather2<<<GATHER_BLOCKS, 256, 0, stream>>>(units, ucnt, ordYX, ordD, featTh, pooled);

    // downsample via MFMA GEMM (swizzled)
    hipMemsetAsync(pooledH, 0, (size_t)DSP1*DSP1*DSC*sizeof(f16), stream);
    hipMemsetAsync(bev1H, 0, (size_t)DSP2*DSP2*DSC*sizeof(f16), stream);
    k_pool2h<<<360, 256, 0, stream>>>(pooled, pooledH);
    k_ds_mfma<2,DSP1,0><<<254, 256, 0, stream>>>(pooledH, WtDS1, ds1_s, ds1_t, bev1H, nullptr);
    k_ds_mfma<1,DSP2,1><<<254, 256, 0, stream>>>(bev1H, WtDS2, ds2_s, ds2_t, nullptr, outp);
}

// Round 18
// 648.961 us; speedup vs baseline: 1.0722x; 1.0133x over previous
//
#include <hip/hip_runtime.h>
#include <math.h>

// ---------------- problem constants ----------------
#define NCAM 6
#define IH 256
#define IW 704
#define FH 32
#define FW 88
#define DD 59
#define CIMG 80
#define NXv 360
#define PIX (FH*FW)           // 2816
#define IMGPIX (IH*IW)        // 180224
#define NPTS (NCAM*DD*PIX)    // 996864
#define NCELLS (NXv*NXv)      // 129600
#define NB 127                // scan blocks
#define UNIT 32
#define MAXUNITS (NCELLS + NPTS/UNIT + 1)   // 160753
#define GATHER_BLOCKS ((MAXUNITS + 3) / 4)  // 40189

// padded GEMM pixel space (depthnet): rows [35] x pitch [96]
#define MPITCH 96
#define MROWS  35
#define MSLAB  (MROWS*MPITCH) // 3360

// dtransform NHWC padded buffers
#define DP_R 260
#define DP_C 708
#define H2_R 68
#define H2_C 180

// BEV ds GEMM
#define DSM   32400
#define DSP1  362
#define DSP2  182
#define DSC   96

typedef _Float16 f16;
typedef f16  f16x8 __attribute__((ext_vector_type(8)));
typedef float f32x4 __attribute__((ext_vector_type(4)));

// XOR-swizzled LDS staging (pitch 32 halves)
#define SWZ(r, g) (((r)<<5) + (((g) ^ ((r)&3))<<3))

// ---------------- ws arena offsets (in floats) ----------------
#define OFF_MATS 0                      // 144
#define OFF_WDS1 144                    // 34,560 (3x80x288 fp16)
#define OFF_WDT2 34704                  // 5,120 (5x32x64 fp16)
#define OFF_WDS2 57744                  // 34,560
// SEG_A: {dNH, h2NH} -> {Q3 + Q2 + Wt1 + Wt2 + Wt3h} -> pooled
#define OFF_A    115344
#define OFF_DNH  OFF_A
#define OFF_H2NH (OFF_A + 4416960)
#define OFF_Q3   OFF_A                  // 6x2816x256 fp16 [dn2..dn3]
#define OFF_Q2   (OFF_A + 4325376)
#define OFF_WT1  (OFF_A + 6905856)      // 9x256x320 fp16
#define OFF_WT2  (OFF_A + 7274496)      // 9x256x256 fp16
#define OFF_TD3  (OFF_A + 7569408)      // Wt3h: 144x256 fp16
// SEG_B
#define OFF_B    10483344
#define OFF_INCL   (OFF_B + 131072)
#define OFF_OFFS   (OFF_B + 262144)
#define OFF_CURSOR (OFF_B + 393216)
#define OFF_BSUM   (OFF_B + 524288)
#define OFF_UCNT   (OFF_B + 524480)
#define OFF_BSX    (OFF_B + 524544)
#define OFF_UNITS  (OFF_B + 525312)
#define OFF_POOLH  (OFF_B)              // 6,289,632 fl
#define OFF_BEV1H  (OFF_B + 6289632)    // 1,590,432 fl — ends 18,363,408
// cnt relocated to the arena tail (after bev1H; nothing else claims it) so it
// can be zeroed inside k_prep_all instead of a dedicated memset dispatch.
#define OFF_CNT  18363408               // 129,600 ints — ends 18,493,008 < 18,853,776
// SEG_C
#define OFF_C    12831888
// SEG_D
#define OFF_D      13913232
#define OFF_Q1     OFF_D
#define OFF_FEATT  OFF_D                // fp16 [16896][80]
#define OFF_FLAT   (OFF_D + 1351680)
#define OFF_ORDYX  (OFF_D + 2348544)
#define OFF_ORDD   (OFF_D + 3345408)
// total 18,853,776 floats ~75.4 MB

// k_prep_all block ranges
#define PB_DS1 0        // 270 blocks: ds1 weights
#define PB_DS2 270      // 270: ds2 weights
#define PB_DT2 540      // 40: dt2 weights
#define PB_DT3 580      // 200: dt3 weights
#define PB_B3  780      // 144: dn3 weights
#define PB_B1  924      // 320: dn1 weights
#define PB_B2  1244     // 256: dn2 weights
#define PB_CM  1500     // 1: cam mats
#define PB_Z   1501     // 1200: zero dNH/h2NH/Q1/cnt
#define PB_TOT 2701
#define ZC0 1104240     // dNH float4 count (4,416,960/4 — stops at OFF_H2NH)
#define ZC1 293760      // h2NH float4 count (1,175,040/4)
#define ZC2 806400      // Q1 float4 count (3,225,600/4)
#define ZC3 32400       // cnt float4 count (129,600/4)

// ---------------- small helpers ----------------
__device__ __forceinline__ void inv3(const float* m, float* o) {
    float a=m[0],b=m[1],c=m[2],d=m[3],e=m[4],f=m[5],g=m[6],h=m[7],i=m[8];
    float A =  (e*i - f*h);
    float B = -(d*i - f*g);
    float C =  (d*h - e*g);
    float det = a*A + b*B + c*C;
    float r = 1.f/det;
    o[0]=A*r;            o[1]=-(b*i - c*h)*r; o[2]=(b*f - c*e)*r;
    o[3]=B*r;            o[4]=(a*i - c*g)*r;  o[5]=-(a*f - c*d)*r;
    o[6]=C*r;            o[7]=-(a*h - b*g)*r; o[8]=(a*e - b*d)*r;
}

// consolidated prep: all weight transforms + cam mats + buffer zeroing
__global__ __launch_bounds__(256) void k_prep_all(
        const float* __restrict__ prot, const float* __restrict__ ptran,
        const float* __restrict__ intr, const float* __restrict__ Rcl,
        const float* __restrict__ tcl,
        const float* __restrict__ ds1_w, const float* __restrict__ ds2_w,
        const float* __restrict__ dt2_w, const float* __restrict__ dt3_w,
        const float* __restrict__ dn3_w, const float* __restrict__ dn1_w,
        const float* __restrict__ dn2_w,
        float* __restrict__ mats,
        f16* __restrict__ WtDS1, f16* __restrict__ WtDS2,
        f16* __restrict__ WtDT2, f16* __restrict__ WtDT3,
        f16* __restrict__ Wt3h,  f16* __restrict__ Wt1, f16* __restrict__ Wt2,
        float* __restrict__ ws) {
    int rb = blockIdx.x;
    int tid = threadIdx.x;
    if (rb < PB_DS2) {                       // ds1 weights
        const float* w = ds1_w; f16* Wt = WtDS1;
        int i = (rb - PB_DS1)*256 + tid;
        if (i < 3*80*288) {
            int k  = i % 288;
            int co = (i / 288) % 80;
            int kx = i / (288*80);
            int ky = k / 96, ci = k % 96;
            Wt[i] = (ci < 80) ? (f16)w[((co*80 + ci)*3 + kx)*3 + ky] : (f16)0.f;
        }
    } else if (rb < PB_DT2) {                // ds2 weights
        const float* w = ds2_w; f16* Wt = WtDS2;
        int i = (rb - PB_DS2)*256 + tid;
        if (i < 3*80*288) {
            int k  = i % 288;
            int co = (i / 288) % 80;
            int kx = i / (288*80);
            int ky = k / 96, ci = k % 96;
            Wt[i] = (ci < 80) ? (f16)w[((co*80 + ci)*3 + kx)*3 + ky] : (f16)0.f;
        }
    } else if (rb < PB_DT3) {                // dt2 weights
        int i = (rb - PB_DT2)*256 + tid;
        if (i < 5*32*64) {
            int ky = i / (32*64);
            int r  = i % (32*64);
            int co = r / 64;
            int k  = r % 64;
            int kx = k / 8, ci = k % 8;
            WtDT2[i] = (kx < 5) ? (f16)dt2_w[co*200 + ci*25 + ky*5 + kx] : (f16)0.f;
        }
    } else if (rb < PB_B3) {                 // dt3 weights
        int i = (rb - PB_DT3)*256 + tid;
        if (i < 5*64*160) {
            int ky = i / (64*160);
            int r  = i % (64*160);
            int co = r / 160;
            int k  = r % 160;
            int kx = k / 32, ci = k % 32;
            WtDT3[i] = (f16)dt3_w[co*800 + ci*25 + ky*5 + kx];
        }
    } else if (rb < PB_B1) {                 // dn3 weights
        int i = (rb - PB_B3)*256 + tid;
        if (i < 144*256) {
            int co = i / 256;
            Wt3h[i] = (co < 139) ? (f16)dn3_w[i] : (f16)0.f;
        }
    } else if (rb < PB_B2) {                 // dn1 weights [9][256][320]
        int i = (rb - PB_B1)*256 + tid;
        if (i < 256*320) {
            int co = i / 320, ci = i % 320;
            const float* src = dn1_w + ((size_t)co*320 + ci)*9;
            #pragma unroll
            for (int t=0;t<9;t++)
                Wt1[((size_t)t*256 + co)*320 + ci] = (f16)src[t];
        }
    } else if (rb < PB_CM) {                 // dn2 weights [9][256][256]
        int i = (rb - PB_B2)*256 + tid;
        if (i < 256*256) {
            int co = i / 256, ci = i % 256;
            const float* src = dn2_w + ((size_t)co*256 + ci)*9;
            #pragma unroll
            for (int t=0;t<9;t++)
                Wt2[((size_t)t*256 + co)*256 + ci] = (f16)src[t];
        }
    } else if (rb < PB_Z) {                  // cam mats
        int n = tid;
        if (n < NCAM) {
            float P[9], Km[9], R[9], A[9], Ki[9];
            for (int i=0;i<9;i++){ P[i]=prot[n*9+i]; Km[i]=intr[n*9+i]; R[i]=Rcl[n*9+i]; }
            inv3(P, A); inv3(Km, Ki);
            float* M = mats + n*24;
            for (int i=0;i<9;i++) M[i] = A[i];
            for (int r=0;r<3;r++)
                M[9+r] = -(A[r*3+0]*ptran[n*3+0] + A[r*3+1]*ptran[n*3+1] + A[r*3+2]*ptran[n*3+2]);
            for (int r=0;r<3;r++) for (int c=0;c<3;c++)
                M[12 + r*3+c] = R[r*3+0]*Ki[0*3+c] + R[r*3+1]*Ki[1*3+c] + R[r*3+2]*Ki[2*3+c];
            for (int r=0;r<3;r++) M[21+r] = tcl[n*3+r];
        }
    } else {                                 // zero dNH + h2NH + Q1 + cnt (grid-stride)
        const float4 z4 = {0.f,0.f,0.f,0.f};
        float4* d0 = (float4*)(ws + OFF_A);
        float4* d1 = (float4*)(ws + OFF_H2NH);
        float4* d2 = (float4*)(ws + OFF_Q1);
        float4* d3 = (float4*)(ws + OFF_CNT);
        size_t total = (size_t)ZC0 + ZC1 + ZC2 + ZC3;
        size_t stride = (size_t)(PB_TOT - PB_Z)*256;
        for (size_t i = (size_t)(rb - PB_Z)*256 + tid; i < total; i += stride) {
            if (i < ZC0) d0[i] = z4;
            else if (i < (size_t)ZC0 + ZC1) d1[i - ZC0] = z4;
            else if (i < (size_t)ZC0 + ZC1 + ZC2) d2[i - ZC0 - ZC1] = z4;
            else d3[i - ZC0 - ZC1 - ZC2] = z4;
        }
    }
}

// fused dt1 -> padded NHWC fp16 [6][260][708][8]
__global__ __launch_bounds__(256) void k_prep_d(const float* __restrict__ d,
                                                const float* __restrict__ w,
                                                const float* __restrict__ b,
                                                const float* __restrict__ s,
                                                const float* __restrict__ t,
                                                f16* __restrict__ dNH) {
    int i = blockIdx.x*256 + threadIdx.x;
    int cam = i / IMGPIX;
    int yx = i % IMGPIX;
    int y = yx / IW, x = yx % IW;
    float v = d[i];
    f16* dst = dNH + ((size_t)cam*DP_R + (y+2))*DP_C*8 + (size_t)(x+2)*8;
    #pragma unroll
    for (int c=0;c<8;c++)
        dst[c] = (f16)fmaxf(fmaf(fmaf(v, w[c], b[c]), s[c], t[c]), 0.f);
}

// dt2 as implicit GEMM (swizzled LDS)
__global__ __launch_bounds__(256) void k_gemm_dt2(const f16* __restrict__ dNH,
                                                  const f16* __restrict__ Wt,
                                                  const float* __restrict__ bias,
                                                  const float* __restrict__ bn_s,
                                                  const float* __restrict__ bn_t,
                                                  f16* __restrict__ h2NH) {
    __shared__ f16 lA[128*32];
    __shared__ f16 lB[32*32];
    int cam = blockIdx.x / 88, mt = blockIdx.x % 88;
    int m0 = mt*128;
    int tid = threadIdx.x;
    int wid = tid>>6, lane = tid&63;
    int wm = wid*32;
    int lr = lane&15, quad = lane>>4;
    int swr = ((quad ^ (lr&3))<<3);
    f32x4 acc[2][2] = {};

    int rr = tid >> 1;
    int g0 = tid & 1, g1 = g0 + 2;
    int am = m0 + rr;
    int ay = am / 176, ax = am % 176;
    const f16* abase = dNH + (size_t)cam*DP_R*DP_C*8 + (size_t)(ay*4)*DP_C*8 + (size_t)(ax*4)*8;

    for (int ky=0; ky<5; ky++) {
        const f16* arow = abase + (size_t)ky*DP_C*8;
        const f16* brow = Wt + ((size_t)ky*32 + rr)*64;
        #pragma unroll
        for (int k0=0; k0<64; k0+=32) {
            *(float4*)(&lA[SWZ(rr,g0)]) = *(const float4*)(arow + k0 + g0*8);
            *(float4*)(&lA[SWZ(rr,g1)]) = *(const float4*)(arow + k0 + g1*8);
            if (tid < 64) {
                *(float4*)(&lB[SWZ(rr,g0)]) = *(const float4*)(brow + k0 + g0*8);
                *(float4*)(&lB[SWZ(rr,g1)]) = *(const float4*)(brow + k0 + g1*8);
            }
            __syncthreads();
            f16x8 af[2], bf[2];
            #pragma unroll
            for (int i=0;i<2;i++) af[i] = *(f16x8*)(&lA[((wm+i*16+lr)<<5) + swr]);
            #pragma unroll
            for (int j=0;j<2;j++) bf[j] = *(f16x8*)(&lB[((j*16+lr)<<5) + swr]);
            #pragma unroll
            for (int i=0;i<2;i++)
                #pragma unroll
                for (int j=0;j<2;j++)
                    acc[i][j] = __builtin_amdgcn_mfma_f32_16x16x32_f16(af[i], bf[j], acc[i][j], 0,0,0);
            __syncthreads();
        }
    }
    #pragma unroll
    for (int j=0;j<2;j++) {
        int n = j*16 + lr;
        float bb = bias[n], ss = bn_s[n], tt = bn_t[n];
        #pragma unroll
        for (int i=0;i<2;i++) {
            #pragma unroll
            for (int r=0;r<4;r++) {
                int m = m0 + wm + i*16 + quad*4 + r;
                int y = m / 176, x = m % 176;
                float v = fmaxf(fmaf(acc[i][j][r] + bb, ss, tt), 0.f);
                h2NH[((size_t)cam*H2_R + (y+2))*H2_C*32 + (size_t)(x+2)*32 + n] = (f16)v;
            }
        }
    }
}

// dt3 as implicit GEMM -> Q1 ch 0..63 (swizzled LDS)
__global__ __launch_bounds__(256) void k_gemm_dt3(const f16* __restrict__ h2NH,
                                                  const f16* __restrict__ Wt,
                                                  const float* __restrict__ bias,
                                                  const float* __restrict__ bn_s,
                                                  const float* __restrict__ bn_t,
                                                  f16* __restrict__ Q1) {
    __shared__ f16 lA[128*32];
    __shared__ f16 lB[64*32];
    int cam = blockIdx.x / 22, mt = blockIdx.x % 22;
    int m0 = mt*128;
    int tid = threadIdx.x;
    int wid = tid>>6, lane = tid&63;
    int wm = wid*32;
    int lr = lane&15, quad = lane>>4;
    int swr = ((quad ^ (lr&3))<<3);
    f32x4 acc[2][4] = {};

    int rr = tid >> 1;
    int g0 = tid & 1, g1 = g0 + 2;
    int am = m0 + rr;
    int ay = am / FW, ax = am % FW;
    const f16* abase = h2NH + (size_t)cam*H2_R*H2_C*32 + (size_t)(ay*2)*H2_C*32 + (size_t)(ax*2)*32;

    for (int ky=0; ky<5; ky++) {
        const f16* arow = abase + (size_t)ky*H2_C*32;
        const f16* brow = Wt + ((size_t)ky*64 + rr)*160;
        #pragma unroll
        for (int k0=0; k0<160; k0+=32) {
            *(float4*)(&lA[SWZ(rr,g0)]) = *(const float4*)(arow + k0 + g0*8);
            *(float4*)(&lA[SWZ(rr,g1)]) = *(const float4*)(arow + k0 + g1*8);
            if (tid < 128) {
                *(float4*)(&lB[SWZ(rr,g0)]) = *(const float4*)(brow + k0 + g0*8);
                *(float4*)(&lB[SWZ(rr,g1)]) = *(const float4*)(brow + k0 + g1*8);
            }
            __syncthreads();
            f16x8 af[2], bf[4];
            #pragma unroll
            for (int i=0;i<2;i++) af[i] = *(f16x8*)(&lA[((wm+i*16+lr)<<5) + swr]);
            #pragma unroll
            for (int j=0;j<4;j++) bf[j] = *(f16x8*)(&lB[((j*16+lr)<<5) + swr]);
            #pragma unroll
            for (int i=0;i<2;i++)
                #pragma unroll
                for (int j=0;j<4;j++)
                    acc[i][j] = __builtin_amdgcn_mfma_f32_16x16x32_f16(af[i], bf[j], acc[i][j], 0,0,0);
            __syncthreads();
        }
    }
    #pragma unroll
    for (int j=0;j<4;j++) {
        int n = j*16 + lr;
        float bb = bias[n], ss = bn_s[n], tt = bn_t[n];
        #pragma unroll
        for (int i=0;i<2;i++) {
            #pragma unroll
            for (int r=0;r<4;r++) {
                int m = m0 + wm + i*16 + quad*4 + r;
                int y = m / FW, x = m % FW;
                float v = fmaxf(fmaf(acc[i][j][r] + bb, ss, tt), 0.f);
                Q1[((size_t)cam*MSLAB + (size_t)(y+1)*MPITCH + (x+1))*320 + n] = (f16)v;
            }
        }
    }
}

// copy x_img -> Q1 channels 64..319
__global__ __launch_bounds__(256) void k_prep_a1x(const float* __restrict__ x_img,
                                                  f16* __restrict__ Q1) {
    __shared__ f16 tile[88*260];
    int y = blockIdx.x, cam = blockIdx.y;
    for (int e = threadIdx.x; e < 88*256; e += 256) {
        int c = e / 88, p = e % 88;
        tile[p*260 + c] = (f16)x_img[((size_t)cam*256 + c)*PIX + y*FW + p];
    }
    __syncthreads();
    f16* dst = Q1 + (size_t)cam*(MSLAB*320) + ((size_t)(y+1)*MPITCH + 1)*320 + 64;
    for (int e = threadIdx.x; e < 88*256; e += 256) {
        int p = e / 256, c = e % 256;
        dst[(size_t)p*320 + c] = tile[p*260 + c];
    }
}

// fp16 implicit-GEMM 3x3 conv (depthnet, swizzled LDS, 128x128)
template<int KCI, int EPI>
__global__ __launch_bounds__(256) void k_gemm_conv(const f16* __restrict__ Aq,
                                                   const f16* __restrict__ Wt,
                                                   const float* __restrict__ bias,
                                                   const float* __restrict__ bn_s,
                                                   const float* __restrict__ bn_t,
                                                   f16* __restrict__ outh) {
    __shared__ f16 lA[128*32];
    __shared__ f16 lB[128*32];
    int cam = blockIdx.x / 24, mt = blockIdx.x % 24;
    int m0 = mt*128;
    int co0 = blockIdx.y * 128;
    int tid = threadIdx.x;
    f32x4 acc[4][4] = {};
    const f16* Abase = Aq + (size_t)cam*MSLAB*KCI;
    int rr = tid >> 1;
    int g0 = tid & 1, g1 = g0 + 2;
    int wid = tid>>6, lane = tid&63;
    int wm = (wid&1)*64, wn = (wid>>1)*64;
    int lr = lane&15, quad = lane>>4;
    int swr = ((quad ^ (lr&3))<<3);

    for (int t=0; t<9; t++) {
        int moff = (t/3)*MPITCH + (t%3);
        const f16* At = Abase + (size_t)(m0 + moff + rr)*KCI;
        const f16* Bt = Wt + ((size_t)t*256 + co0 + rr)*KCI;
        for (int k0=0; k0<KCI; k0+=32) {
            *(float4*)(&lA[SWZ(rr,g0)]) = *(const float4*)(At + k0 + g0*8);
            *(float4*)(&lA[SWZ(rr,g1)]) = *(const float4*)(At + k0 + g1*8);
            *(float4*)(&lB[SWZ(rr,g0)]) = *(const float4*)(Bt + k0 + g0*8);
            *(float4*)(&lB[SWZ(rr,g1)]) = *(const float4*)(Bt + k0 + g1*8);
            __syncthreads();
            f16x8 af[4], bf[4];
            #pragma unroll
            for (int i=0;i<4;i++) af[i] = *(f16x8*)(&lA[((wm+i*16+lr)<<5) + swr]);
            #pragma unroll
            for (int j=0;j<4;j++) bf[j] = *(f16x8*)(&lB[((wn+j*16+lr)<<5) + swr]);
            #pragma unroll
            for (int i=0;i<4;i++)
                #pragma unroll
                for (int j=0;j<4;j++)
                    acc[i][j] = __builtin_amdgcn_mfma_f32_16x16x32_f16(af[i], bf[j], acc[i][j], 0,0,0);
            __syncthreads();
        }
    }
    #pragma unroll
    for (int j=0;j<4;j++) {
        int n = co0 + wn + j*16 + lr;
        float bb = bias[n], ss = bn_s[n], tt = bn_t[n];
        #pragma unroll
        for (int i=0;i<4;i++) {
            #pragma unroll
            for (int r=0;r<4;r++) {
                int m = m0 + wm + i*16 + quad*4 + r;
                int y = m / MPITCH, x = m % MPITCH;
                if (x >= FW || y >= FH) continue;
                float v = fmaxf(fmaf(acc[i][j][r] + bb, ss, tt), 0.f);
                if (EPI == 0)
                    outh[((size_t)cam*MSLAB + (size_t)(y+1)*MPITCH + (x+1))*256 + n] = (f16)v;
                else
                    outh[((size_t)cam*PIX + (size_t)(y*FW + x))*256 + n] = (f16)v;
            }
        }
    }
}

// dn3 as MFMA GEMM (M=2816/cam, N=144, K=256) -> f3 fp32 NCHW
__global__ __launch_bounds__(256) void k_gemm_dn3(const f16* __restrict__ Q3,
                                                  const f16* __restrict__ Wt,
                                                  const float* __restrict__ bias,
                                                  float* __restrict__ f3) {
    __shared__ f16 lA[128*32];
    __shared__ f16 lB[144*32];
    int cam = blockIdx.x / 22, mt = blockIdx.x % 22;
    int m0 = mt*128;
    int tid = threadIdx.x;
    int wid = tid>>6, lane = tid&63;
    int wm = wid*32;
    int lr = lane&15, quad = lane>>4;
    int swr = ((quad ^ (lr&3))<<3);
    f32x4 acc[2][9] = {};

    int rr = tid >> 1;
    int g0 = tid & 1, g1 = g0 + 2;
    const f16* abase = Q3 + ((size_t)cam*PIX + m0 + rr)*256;
    const f16* bbase = Wt + (size_t)tid*256;

    for (int k0=0; k0<256; k0+=32) {
        *(float4*)(&lA[SWZ(rr,g0)]) = *(const float4*)(abase + k0 + g0*8);
        *(float4*)(&lA[SWZ(rr,g1)]) = *(const float4*)(abase + k0 + g1*8);
        if (tid < 144) {
            #pragma unroll
            for (int g=0; g<4; g++)
                *(float4*)(&lB[SWZ(tid,g)]) = *(const float4*)(bbase + k0 + g*8);
        }
        __syncthreads();
        f16x8 af[2], bf[9];
        #pragma unroll
        for (int i=0;i<2;i++) af[i] = *(f16x8*)(&lA[((wm+i*16+lr)<<5) + swr]);
        #pragma unroll
        for (int j=0;j<9;j++) bf[j] = *(f16x8*)(&lB[((j*16+lr)<<5) + swr]);
        #pragma unroll
        for (int i=0;i<2;i++)
            #pragma unroll
            for (int j=0;j<9;j++)
                acc[i][j] = __builtin_amdgcn_mfma_f32_16x16x32_f16(af[i], bf[j], acc[i][j], 0,0,0);
        __syncthreads();
    }
    #pragma unroll
    for (int j=0;j<9;j++) {
        int n = j*16 + lr;
        if (n >= 139) continue;
        float bb = bias[n];
        #pragma unroll
        for (int i=0;i<2;i++) {
            #pragma unroll
            for (int r=0;r<4;r++) {
                int m = m0 + wm + i*16 + quad*4 + r;
                f3[((size_t)cam*139 + n)*PIX + m] = acc[i][j][r] + bb;
            }
        }
    }
}

// post: softmax (blocks 0..65) + featT transpose (blocks 66..257), merged
__global__ __launch_bounds__(256) void k_post(const float* __restrict__ f3,
                                              float* __restrict__ depth,
                                              f16* __restrict__ featTh) {
    __shared__ float tile[88*81];
    int rb = blockIdx.x;
    if (rb < 66) {
        // softmax: register-cached single pass over the 59 depth logits
        int o = rb*256 + threadIdx.x;       // 16896
        int n = o / PIX, yx = o % PIX;
        const float* fp = f3 + (size_t)n*139*PIX + yx;
        float r[DD];
        #pragma unroll
        for (int d=0; d<DD; d++) r[d] = fp[(size_t)d*PIX];
        float m = -1e30f;
        #pragma unroll
        for (int d=0; d<DD; d++) m = fmaxf(m, r[d]);
        float sum = 0.f;
        #pragma unroll
        for (int d=0; d<DD; d++) { r[d] = expf(r[d]-m); sum += r[d]; }
        float inv = 1.f/sum;
        #pragma unroll
        for (int d=0; d<DD; d++)
            depth[((size_t)n*DD+d)*PIX + yx] = r[d]*inv;
    } else {
        // featT: f3 ch 59..138 -> fp16 [n*PIX+yx][80], LDS-tiled
        int idx = rb - 66;                  // 0..191
        int y = idx % 32, cam = idx / 32;
        const float* src = f3 + (size_t)cam*139*PIX + (size_t)DD*PIX + y*FW;
        for (int e = threadIdx.x; e < 88*80; e += 256) {
            int c = e / 88, p = e % 88;
            tile[p*81 + c] = src[(size_t)c*PIX + p];
        }
        __syncthreads();
        f16* dst = featTh + ((size_t)cam*PIX + y*FW)*CIMG;
        for (int e = threadIdx.x; e < 88*80; e += 256) {
            int p = e / 80, c = e % 80;
            dst[(size_t)p*CIMG + c] = (f16)tile[p*81 + c];
        }
    }
}

// frustum -> voxel index + histogram
__global__ __launch_bounds__(256) void k_voxel(const float* __restrict__ mats, int* __restrict__ flat,
                                               int* __restrict__ cnt) {
    int p = blockIdx.x*256 + threadIdx.x;
    if (p >= NPTS) return;
    int x = p % FW; int t1 = p / FW;
    int y = t1 % FH; int t2 = t1 / FH;
    int dd = t2 % DD; int n = t2 / DD;
    float xf = x * (703.f/87.f);
    float yf = y * (255.f/31.f);
    float df = 1.f + (float)dd;
    const float* M = mats + n*24;
    float qx = M[0]*xf + M[1]*yf + M[2]*df + M[9];
    float qy = M[3]*xf + M[4]*yf + M[5]*df + M[10];
    float qz = M[6]*xf + M[7]*yf + M[8]*df + M[11];
    float rx = qx*qz, ry = qy*qz, rz = qz;
    float wx = M[12]*rx + M[13]*ry + M[14]*rz + M[21];
    float wy = M[15]*rx + M[16]*ry + M[17]*rz + M[22];
    float wz = M[18]*rx + M[19]*ry + M[20]*rz + M[23];
    int gx = (int)((wx + 54.f) / 0.3f);
    int gy = (int)((wy + 54.f) / 0.3f);
    int gz = (int)((wz + 10.f) / 20.f);
    bool kept = ((unsigned)gx < NXv) && ((unsigned)gy < NXv) && (gz == 0);
    int cell = kept ? (gx*NXv + gy) : -1;
    flat[p] = cell;
    if (kept) atomicAdd(&cnt[cell], 1);
}

// scan step 1
__global__ __launch_bounds__(256) void k_scan1(const int* __restrict__ cnt, int* __restrict__ incl,
                                               int* __restrict__ bsum) {
    int tid = threadIdx.x;
    int idx = blockIdx.x*1024 + tid*4;
    int c0 = (idx+0 < NCELLS) ? cnt[idx+0] : 0;
    int c1 = (idx+1 < NCELLS) ? cnt[idx+1] : 0;
    int c2 = (idx+2 < NCELLS) ? cnt[idx+2] : 0;
    int c3 = (idx+3 < NCELLS) ? cnt[idx+3] : 0;
    int s0=c0, s1=s0+c1, s2=s1+c2, s3=s2+c3;
    int v = s3;
    int lane = tid & 63, wid = tid >> 6;
    #pragma unroll
    for (int d=1; d<64; d<<=1) {
        int u = __shfl_up(v, d, 64);
        if (lane >= d) v += u;
    }
    __shared__ int wsum[4];
    if (lane == 63) wsum[wid] = v;
    __syncthreads();
    int woff = 0;
    #pragma unroll
    for (int w=0; w<3; w++) if (w < wid) woff += wsum[w];
    int texcl = woff + v - s3;
    if (idx+0 < NCELLS) incl[idx+0] = texcl + s0;
    if (idx+1 < NCELLS) incl[idx+1] = texcl + s1;
    if (idx+2 < NCELLS) incl[idx+2] = texcl + s2;
    if (idx+3 < NCELLS) incl[idx+3] = texcl + s3;
    if (tid == 255) bsum[blockIdx.x] = woff + v;
}

// scan step 2
__global__ void k_scan2(const int* __restrict__ bsum, int* __restrict__ bsx,
                        int* __restrict__ ucount) {
    int lane = threadIdx.x;
    if (lane == 0) *ucount = 0;
    int a = (2*lane   < NB) ? bsum[2*lane]   : 0;
    int b = (2*lane+1 < NB) ? bsum[2*lane+1] : 0;
    int s = a + b;
    int v = s;
    #pragma unroll
    for (int d=1; d<64; d<<=1) {
        int u = __shfl_up(v, d, 64);
        if (lane >= d) v += u;
    }
    int excl = v - s;
    if (2*lane   < NB) bsx[2*lane]   = excl;
    if (2*lane+1 < NB) bsx[2*lane+1] = excl + a;
}

// scan step 3: offsets + cursor + work units (k>0 only)
__global__ __launch_bounds__(256) void k_scan3(const int* __restrict__ incl, const int* __restrict__ cnt,
                                               const int* __restrict__ bsx, int* __restrict__ offs,
                                               int* __restrict__ cursor,
                                               int* __restrict__ units, int* __restrict__ ucount) {
    int idx = blockIdx.x*1024 + threadIdx.x*4;
    int o = bsx[blockIdx.x];
    #pragma unroll
    for (int j=0;j<4;j++) {
        int cell = idx + j;
        if (cell < NCELLS) {
            int k = cnt[cell];
            int e = o + incl[cell] - k;
            offs[cell] = e;
            cursor[cell] = e;
            if (k > 0) {
                int nu = (k + UNIT-1) / UNIT;
                int ub = atomicAdd(ucount, nu);
                int multi = (nu > 1) ? (1<<17) : 0;
                for (int u=0; u<nu; u++) {
                    int c2 = min(UNIT, k - u*UNIT);
                    units[2*(ub+u)]   = cell | multi | (c2<<18);
                    units[2*(ub+u)+1] = e + u*UNIT;
                }
            }
        }
    }
}

// bucket points: pre-resolved (feat row, depth)
__global__ __launch_bounds__(256) void k_fill(const int* __restrict__ flat, int* __restrict__ cursor,
                                              const float* __restrict__ depth,
                                              int* __restrict__ ordYX, float* __restrict__ ordD) {
    int p = blockIdx.x*256 + threadIdx.x;
    if (p >= NPTS) return;
    int cell = flat[p];
    if (cell < 0) return;
    int pos = atomicAdd(&cursor[cell], 1);
    int n = p / (DD*PIX);
    int yx = p % PIX;
    ordYX[pos] = n*PIX + yx;
    ordD[pos] = depth[p];
}

// gather v3: fp16 featT rows
__global__ __launch_bounds__(256) void k_gather2(const int* __restrict__ units,
                                                 const int* __restrict__ ucount,
                                                 const int* __restrict__ ordYX,
                                                 const float* __restrict__ ordD,
                                                 const f16* __restrict__ featTh,
                                                 float* __restrict__ pooled) {
    int idx = blockIdx.x*4 + (threadIdx.x >> 6);
    if (idx >= *ucount) return;
    int lane = threadIdx.x & 63;
    int u0 = units[2*idx], base = units[2*idx+1];
    int cell = u0 & 0x1ffff;
    bool multi = (u0 >> 17) & 1;
    int count = u0 >> 18;
    float acc0 = 0.f, acc1 = 0.f;
    bool lo = (lane < 16);
    int i = 0;
    for (; i+2 <= count; i += 2) {
        int y0 = ordYX[base+i], y1 = ordYX[base+i+1];
        float d0 = ordD[base+i], d1 = ordD[base+i+1];
        const f16* f0 = featTh + (size_t)y0*CIMG;
        const f16* f1 = featTh + (size_t)y1*CIMG;
        float a = (float)f0[lane];
        float b = (float)f1[lane];
        float c = lo ? (float)f0[64+lane] : 0.f;
        float d = lo ? (float)f1[64+lane] : 0.f;
        acc0 = fmaf(d0, a, acc0);
        acc0 = fmaf(d1, b, acc0);
        acc1 = fmaf(d0, c, acc1);
        acc1 = fmaf(d1, d, acc1);
    }
    if (i < count) {
        int y0 = ordYX[base+i];
        float d0 = ordD[base+i];
        const f16* f0 = featTh + (size_t)y0*CIMG;
        acc0 = fmaf(d0, (float)f0[lane], acc0);
        if (lo) acc1 = fmaf(d0, (float)f0[64+lane], acc1);
    }
    float* dst = pooled + (size_t)cell*CIMG;
    if (multi) {
        atomicAdd(dst + lane, acc0);
        if (lo) atomicAdd(dst + 64 + lane, acc1);
    } else {
        dst[lane] = acc0;
        if (lo) dst[64 + lane] = acc1;
    }
}

// pooled fp32 -> padded NHWC fp16 [362][362][96]
__global__ __launch_bounds__(256) void k_pool2h(const float* __restrict__ pooled,
                                                f16* __restrict__ pooledH) {
    int gx = blockIdx.x;
    const float* src = pooled + (size_t)gx*360*80;
    for (int e = threadIdx.x; e < 360*80; e += 256) {
        int gy = e / 80, c = e % 80;
        pooledH[((size_t)(gx+1)*DSP1 + (gy+1))*DSC + c] = (f16)src[e];
    }
}

// BEV downsample as fp16 MFMA implicit GEMM (swizzled LDS)
template<int STRIDE, int HINP, int EPI>
__global__ __launch_bounds__(256) void k_ds_mfma(const f16* __restrict__ inH,
                                                 const f16* __restrict__ Wt,
                                                 const float* __restrict__ bn_s,
                                                 const float* __restrict__ bn_t,
                                                 f16* __restrict__ outh,
                                                 float* __restrict__ outf) {
    __shared__ f16 lA[128*32];
    __shared__ f16 lB[80*32];
    int m0 = blockIdx.x * 128;
    int tid = threadIdx.x;
    int wid = tid>>6, lane = tid&63;
    int wm = wid*32;
    int lr = lane&15, quad = lane>>4;
    int swr = ((quad ^ (lr&3))<<3);
    f32x4 acc[2][5] = {};

    int rr = tid >> 1;
    int g0 = tid & 1, g1 = g0 + 2;
    int am = min(m0 + rr, DSM-1);
    int axo = am / 180, ayo = am % 180;
    const f16* arow0 = inH + ((size_t)(axo*STRIDE)*HINP + (size_t)ayo*STRIDE)*DSC;
    const f16* brow0 = Wt + (size_t)rr*288;

    for (int kx=0; kx<3; kx++) {
        const f16* arow = arow0 + (size_t)kx*HINP*DSC;
        const f16* brow = brow0 + (size_t)kx*80*288;
        for (int k0=0; k0<288; k0+=32) {
            *(float4*)(&lA[SWZ(rr,g0)]) = *(const float4*)(arow + k0 + g0*8);
            *(float4*)(&lA[SWZ(rr,g1)]) = *(const float4*)(arow + k0 + g1*8);
            if (tid < 160) {
                *(float4*)(&lB[SWZ(rr,g0)]) = *(const float4*)(brow + k0 + g0*8);
                *(float4*)(&lB[SWZ(rr,g1)]) = *(const float4*)(brow + k0 + g1*8);
            }
            __syncthreads();
            f16x8 af[2], bf[5];
            #pragma unroll
            for (int i=0;i<2;i++) af[i] = *(f16x8*)(&lA[((wm+i*16+lr)<<5) + swr]);
            #pragma unroll
            for (int j=0;j<5;j++) bf[j] = *(f16x8*)(&lB[((j*16+lr)<<5) + swr]);
            #pragma unroll
            for (int i=0;i<2;i++)
                #pragma unroll
                for (int j=0;j<5;j++)
                    acc[i][j] = __builtin_amdgcn_mfma_f32_16x16x32_f16(af[i], bf[j], acc[i][j], 0,0,0);
            __syncthreads();
        }
    }
    #pragma unroll
    for (int j=0;j<5;j++) {
        int n = j*16 + lr;
        float ss = bn_s[n], tt = bn_t[n];
        #pragma unroll
        for (int i=0;i<2;i++) {
            #pragma unroll
            for (int r=0;r<4;r++) {
                int m = m0 + wm + i*16 + quad*4 + r;
                if (m >= DSM) continue;
                float v = fmaxf(fmaf(acc[i][j][r], ss, tt), 0.f);
                if (EPI == 0) {
                    int xo = m / 180, yo = m % 180;
                    outh[((size_t)(xo+1)*DSP2 + (yo+1))*DSC + n] = (f16)v;
                } else {
                    outf[(size_t)n*DSM + m] = v;
                }
            }
        }
    }
}

// ---------------- host launcher ----------------
extern "C" void kernel_launch(void* const* d_in, const int* in_sizes, int n_in,
                              void* d_out, int out_size, void* d_ws, size_t ws_size,
                              hipStream_t stream) {
    const float* x_img  = (const float*)d_in[0];
    const float* dimg   = (const float*)d_in[1];
    const float* c2l_R  = (const float*)d_in[2];
    const float* c2l_t  = (const float*)d_in[3];
    const float* intr   = (const float*)d_in[4];
    const float* prot   = (const float*)d_in[5];
    const float* ptran  = (const float*)d_in[6];
    const float* dt1_w  = (const float*)d_in[7];
    const float* dt1_b  = (const float*)d_in[8];
    const float* dt1_s  = (const float*)d_in[9];
    const float* dt1_t  = (const float*)d_in[10];
    const float* dt2_w  = (const float*)d_in[11];
    const float* dt2_b  = (const float*)d_in[12];
    const float* dt2_s  = (const float*)d_in[13];
    const float* dt2_t  = (const float*)d_in[14];
    const float* dt3_w  = (const float*)d_in[15];
    const float* dt3_b  = (const float*)d_in[16];
    const float* dt3_s  = (const float*)d_in[17];
    const float* dt3_t  = (const float*)d_in[18];
    const float* dn1_w  = (const float*)d_in[19];
    const float* dn1_b  = (const float*)d_in[20];
    const float* dn1_s  = (const float*)d_in[21];
    const float* dn1_t  = (const float*)d_in[22];
    const float* dn2_w  = (const float*)d_in[23];
    const float* dn2_b  = (const float*)d_in[24];
    const float* dn2_s  = (const float*)d_in[25];
    const float* dn2_t  = (const float*)d_in[26];
    const float* dn3_w  = (const float*)d_in[27];
    const float* dn3_b  = (const float*)d_in[28];
    const float* ds1_w  = (const float*)d_in[29];
    const float* ds1_s  = (const float*)d_in[30];
    const float* ds1_t  = (const float*)d_in[31];
    const float* ds2_w  = (const float*)d_in[32];
    const float* ds2_s  = (const float*)d_in[33];
    const float* ds2_t  = (const float*)d_in[34];

    float* ws = (float*)d_ws;
    float* mats   = ws + OFF_MATS;
    f16*   WtDS1  = (f16*)(ws + OFF_WDS1);
    f16*   WtDS2  = (f16*)(ws + OFF_WDS2);
    f16*   WtDT2  = (f16*)(ws + OFF_WDT2);
    f16*   WtDT3  = (f16*)(ws + OFF_B);      // dead scratch until scan
    f16*   dNH    = (f16*)(ws + OFF_DNH);
    f16*   h2NH   = (f16*)(ws + OFF_H2NH);
    f16*   Q3     = (f16*)(ws + OFF_Q3);
    float* pooled = ws + OFF_A;
    f16*   Q2     = (f16*)(ws + OFF_Q2);
    f16*   Wt1    = (f16*)(ws + OFF_WT1);
    f16*   Wt2    = (f16*)(ws + OFF_WT2);
    f16*   Wt3h   = (f16*)(ws + OFF_TD3);
    float* f3     = ws + OFF_B;
    int*   cnt    = (int*)(ws + OFF_CNT);    // arena tail, zeroed in k_prep_all
    int*   incl   = (int*)(ws + OFF_INCL);
    int*   offs   = (int*)(ws + OFF_OFFS);
    int*   cursor = (int*)(ws + OFF_CURSOR);
    int*   bsum   = (int*)(ws + OFF_BSUM);
    int*   ucnt   = (int*)(ws + OFF_UCNT);
    int*   bsx    = (int*)(ws + OFF_BSX);
    int*   units  = (int*)(ws + OFF_UNITS);
    f16*   pooledH= (f16*)(ws + OFF_POOLH);
    f16*   bev1H  = (f16*)(ws + OFF_BEV1H);
    float* depth  = ws + OFF_C;
    f16*   Q1     = (f16*)(ws + OFF_Q1);
    f16*   featTh = (f16*)(ws + OFF_FEATT);
    int*   flat   = (int*)(ws + OFF_FLAT);
    int*   ordYX  = (int*)(ws + OFF_ORDYX);
    float* ordD   = ws + OFF_ORDD;
    float* outp   = (float*)d_out;

    // consolidated prep: weight transforms + cam mats + dNH/h2NH/Q1/cnt zeroing
    k_prep_all<<<PB_TOT, 256, 0, stream>>>(prot, ptran, intr, c2l_R, c2l_t,
                                           ds1_w, ds2_w, dt2_w, dt3_w, dn3_w, dn1_w, dn2_w,
                                           mats, WtDS1, WtDS2, WtDT2, WtDT3, Wt3h, Wt1, Wt2, ws);

    // dtransform via MFMA GEMM
    k_prep_d<<<4224, 256, 0, stream>>>(dimg, dt1_w, dt1_b, dt1_s, dt1_t, dNH);
    k_gemm_dt2<<<528, 256, 0, stream>>>(dNH, WtDT2, dt2_b, dt2_s, dt2_t, h2NH);
    k_gemm_dt3<<<132, 256, 0, stream>>>(h2NH, WtDT3, dt3_b, dt3_s, dt3_t, Q1);
    k_prep_a1x<<<dim3(32,NCAM), 256, 0, stream>>>(x_img, Q1);

    // depthnet via MFMA GEMM (swizzled LDS, 128x128)
    hipMemsetAsync(Q2, 0, (size_t)NCAM*MSLAB*256*sizeof(f16), stream);
    k_gemm_conv<320,0><<<dim3(144,2), 256, 0, stream>>>(Q1, Wt1, dn1_b, dn1_s, dn1_t, Q2);
    k_gemm_conv<256,1><<<dim3(144,2), 256, 0, stream>>>(Q2, Wt2, dn2_b, dn2_s, dn2_t, Q3);
    k_gemm_dn3<<<132, 256, 0, stream>>>(Q3, Wt3h, dn3_b, f3);

    // softmax + featT (merged)
    k_post<<<258, 256, 0, stream>>>(f3, depth, featTh);

    // bev_pool (cnt pre-zeroed in k_prep_all; pooled memset required for atomics)
    hipMemsetAsync(pooled, 0, (size_t)NCELLS*CIMG*sizeof(float), stream);
    k_voxel<<<3894, 256, 0, stream>>>(mats, flat, cnt);
    k_scan1<<<NB, 256, 0, stream>>>(cnt, incl, bsum);
    k_scan2<<<1, 64, 0, stream>>>(bsum, bsx, ucnt);
    k_scan3<<<NB, 256, 0, stream>>>(incl, cnt, bsx, offs, cursor, units, ucnt);
    k_fill<<<3894, 256, 0, stream>>>(flat, cursor, depth, ordYX, ordD);
    k_gather2<<<GATHER_BLOCKS, 256, 0, stream>>>(units, ucnt, ordYX, ordD, featTh, pooled);

    // downsample via MFMA GEMM (pooledH+bev1H are contiguous -> one memset)
    hipMemsetAsync(pooledH, 0, ((size_t)DSP1*DSP1 + (size_t)DSP2*DSP2)*DSC*sizeof(f16), stream);
    k_pool2h<<<360, 256, 0, stream>>>(pooled, pooledH);
    k_ds_mfma<2,DSP1,0><<<254, 256, 0, stream>>>(pooledH, WtDS1, ds1_s, ds1_t, bev1H, nullptr);
    k_ds_mfma<1,DSP2,1><<<254, 256, 0, stream>>>(bev1H, WtDS2, ds2_s, ds2_t, nullptr, outp);
}